// Round 1
// baseline (899.888 us; speedup 1.0000x reference)
//
#include <hip/hip_runtime.h>
#include <hip/hip_bf16.h>
#include <math.h>

typedef __bf16 bf16_t;
typedef __attribute__((ext_vector_type(8))) __bf16 bf16x8;
typedef __attribute__((ext_vector_type(4))) __bf16 bf16x4;
typedef __attribute__((ext_vector_type(4))) float f32x4;

#define LN_EPS 1e-5f
#define RADIUS_F 16.0f

__device__ inline bf16x8 zero8() {
    bf16x8 v;
#pragma unroll
    for (int i = 0; i < 8; ++i) v[i] = (__bf16)0.f;
    return v;
}

__device__ inline float wave_sum(float v) {
#pragma unroll
    for (int o = 1; o < 64; o <<= 1) v += __shfl_xor(v, o);
    return v;
}

// ---------------- casts ----------------
__global__ __launch_bounds__(256) void cast_k(const float* __restrict__ in,
                                              bf16_t* __restrict__ out, int n4) {
    int i = blockIdx.x * 256 + threadIdx.x;
    if (i < n4) {
        float4 v = reinterpret_cast<const float4*>(in)[i];
        bf16x4 o;
        o[0] = (__bf16)v.x; o[1] = (__bf16)v.y; o[2] = (__bf16)v.z; o[3] = (__bf16)v.w;
        reinterpret_cast<bf16x4*>(out)[i] = o;
    }
}

// normalize mem_key rows (896 x 64) -> bf16
__global__ __launch_bounds__(256) void keyn_k(const float* __restrict__ mk,
                                              bf16_t* __restrict__ kn) {
    int row = blockIdx.x * 4 + (threadIdx.x >> 6);
    int lane = threadIdx.x & 63;
    float x = mk[(size_t)row * 64 + lane];
    float ss = wave_sum(x * x);
    kn[(size_t)row * 64 + lane] = (__bf16)(x / fmaxf(sqrtf(ss), 1e-12f));
}

// mem_value: row inv-norms + bf16 copy; also zero the two loss slots
__global__ __launch_bounds__(256) void mv_prep_k(const float* __restrict__ mv,
                                                 bf16_t* __restrict__ mvb,
                                                 float* __restrict__ invmv,
                                                 float* __restrict__ loss_slots) {
    const int s = blockIdx.x, tid = threadIdx.x;
    float2 x = *reinterpret_cast<const float2*>(mv + (size_t)s * 512 + tid * 2);
    float ss = wave_sum(x.x * x.x + x.y * x.y);
    __shared__ float red[4];
    int wid = tid >> 6, lane = tid & 63;
    if (lane == 0) red[wid] = ss;
    __syncthreads();
    ss = red[0] + red[1] + red[2] + red[3];
    if (tid == 0) invmv[s] = 1.f / fmaxf(sqrtf(ss), 1e-12f);
    mvb[(size_t)s * 512 + tid * 2] = (__bf16)x.x;
    mvb[(size_t)s * 512 + tid * 2 + 1] = (__bf16)x.y;
    if (s == 0 && tid < 2) loss_slots[tid] = 0.f;
}

// mem_value transposed + zero-padded to [512][128] bf16
__global__ __launch_bounds__(256) void mvT_k(const float* __restrict__ mv,
                                             bf16_t* __restrict__ mvT) {
    int idx = blockIdx.x * 256 + threadIdx.x;  // 512*128
    int j = idx >> 7, s = idx & 127;
    mvT[idx] = (__bf16)(s < 112 ? mv[(size_t)s * 512 + j] : 0.f);
}

// contrastive loss: sum |I - Gn Gn^T| * 0.01  (fp32)
__global__ __launch_bounds__(256) void contrastive_k(const float* __restrict__ mv,
                                                     const float* __restrict__ invmv,
                                                     float* __restrict__ out_slot) {
    const int a = blockIdx.x;
    const int tid = threadIdx.x, wid = tid >> 6, lane = tid & 63;
    __shared__ float rowa[512];
    __shared__ float wsum[4];
    for (int i = tid; i < 512; i += 256) rowa[i] = mv[(size_t)a * 512 + i];
    __syncthreads();
    float acc = 0.f;
    const float ia = invmv[a];
    for (int b = wid; b < 112; b += 4) {
        float d = 0.f;
#pragma unroll
        for (int i = 0; i < 8; ++i) d += rowa[lane + i * 64] * mv[(size_t)b * 512 + lane + i * 64];
        d = wave_sum(d);
        float gv = d * ia * invmv[b];
        acc += fabsf((a == b ? 1.f : 0.f) - gv);
    }
    if (lane == 0) wsum[wid] = acc;
    __syncthreads();
    if (tid == 0) atomicAdd(out_slot, (wsum[0] + wsum[1] + wsum[2] + wsum[3]) * 0.01f);
}

// ---------------- generic direct-global MFMA GEMM ----------------
// C[M,N] = A[M,K](bf16) * W[N,K]^T(bf16) (+bias[col]); out fp32 (Cf) or bf16 (Cb)
// blockIdx.z adds element offsets aZ/wZ/cZ (for per-head slices).
__global__ __launch_bounds__(256) void gemm_bt(
    const bf16_t* __restrict__ A, int lda, int aZ,
    const bf16_t* __restrict__ W, int ldw, int wZ,
    const float* __restrict__ bias,
    float* __restrict__ Cf, bf16_t* __restrict__ Cb, int ldc, int cZ,
    int M, int N, int K) {
    const int wid = threadIdx.x >> 6;
    const int lane = threadIdx.x & 63;
    const int lr = lane & 15;
    const int kk = (lane >> 4) * 8;
    const int row0 = blockIdx.x * 64 + wid * 16;
    const int col0 = blockIdx.y * 64;
    A += (size_t)blockIdx.z * aZ;
    W += (size_t)blockIdx.z * wZ;
    const bf16_t* a_ptr = A + (size_t)(row0 + lr) * lda + kk;
    const bf16_t* w_ptr = W + (size_t)(col0 + lr) * ldw + kk;
    f32x4 acc[4];
#pragma unroll
    for (int t = 0; t < 4; ++t) { acc[t][0] = 0.f; acc[t][1] = 0.f; acc[t][2] = 0.f; acc[t][3] = 0.f; }
    bool colv[4];
#pragma unroll
    for (int t = 0; t < 4; ++t) colv[t] = (col0 + t * 16 + lr) < N;
    for (int k0 = 0; k0 < K; k0 += 32) {
        bf16x8 a = *reinterpret_cast<const bf16x8*>(a_ptr + k0);
#pragma unroll
        for (int t = 0; t < 4; ++t) {
            bf16x8 b;
            if (colv[t]) b = *reinterpret_cast<const bf16x8*>(w_ptr + (size_t)t * 16 * ldw + k0);
            else b = zero8();
            acc[t] = __builtin_amdgcn_mfma_f32_16x16x32_bf16(a, b, acc[t], 0, 0, 0);
        }
    }
    const int rb = (lane >> 4) * 4;
    if (Cf) Cf += (size_t)blockIdx.z * cZ;
    if (Cb) Cb += (size_t)blockIdx.z * cZ;
#pragma unroll
    for (int t = 0; t < 4; ++t) {
        int col = col0 + t * 16 + lr;
        if (col >= N) continue;
        float bv = bias ? bias[col] : 0.f;
#pragma unroll
        for (int j = 0; j < 4; ++j) {
            int r = row0 + rb + j;
            float v = acc[t][j] + bv;
            if (Cf) Cf[(size_t)r * ldc + col] = v;
            else Cb[(size_t)r * ldc + col] = (__bf16)v;
        }
    }
}

// ---------------- predict addressing: sim -> softmax -> addr bf16 [N,896] ----------------
__global__ __launch_bounds__(256) void addr_predict(const bf16_t* __restrict__ qp,
                                                    const bf16_t* __restrict__ keyn,
                                                    bf16_t* __restrict__ addr) {
    const int wid = threadIdx.x >> 6, lane = threadIdx.x & 63;
    const int lr = lane & 15, kk = (lane >> 4) * 8;
    const int h = blockIdx.y;
    const int row0 = blockIdx.x * 64 + wid * 16;
    const bf16_t* a_ptr = qp + (size_t)(row0 + lr) * 512 + h * 64 + kk;
    bf16x8 a0 = *reinterpret_cast<const bf16x8*>(a_ptr);
    bf16x8 a1 = *reinterpret_cast<const bf16x8*>(a_ptr + 32);
    float ssq = 0.f;
#pragma unroll
    for (int j = 0; j < 8; ++j) {
        float x = (float)a0[j], y = (float)a1[j];
        ssq += x * x + y * y;
    }
    ssq += __shfl_xor(ssq, 16);
    ssq += __shfl_xor(ssq, 32);
    const float invq = 1.f / fmaxf(sqrtf(ssq), 1e-12f);
    f32x4 acc[7];
#pragma unroll
    for (int t = 0; t < 7; ++t) {
        const bf16_t* b_ptr = keyn + (size_t)(h * 112 + t * 16 + lr) * 64 + kk;
        bf16x8 b0 = *reinterpret_cast<const bf16x8*>(b_ptr);
        bf16x8 b1 = *reinterpret_cast<const bf16x8*>(b_ptr + 32);
        f32x4 c; c[0] = 0.f; c[1] = 0.f; c[2] = 0.f; c[3] = 0.f;
        c = __builtin_amdgcn_mfma_f32_16x16x32_bf16(a0, b0, c, 0, 0, 0);
        c = __builtin_amdgcn_mfma_f32_16x16x32_bf16(a1, b1, c, 0, 0, 0);
        acc[t] = c;
    }
    const int rb = (lane >> 4) * 4;
    float iq[4];
#pragma unroll
    for (int j = 0; j < 4; ++j) iq[j] = __shfl(invq, rb + j);
#pragma unroll
    for (int j = 0; j < 4; ++j) {
        float m = -1e30f;
#pragma unroll
        for (int t = 0; t < 7; ++t) { acc[t][j] *= iq[j] * RADIUS_F; m = fmaxf(m, acc[t][j]); }
#pragma unroll
        for (int o = 1; o < 16; o <<= 1) m = fmaxf(m, __shfl_xor(m, o));
        float s = 0.f;
#pragma unroll
        for (int t = 0; t < 7; ++t) { float e = __expf(acc[t][j] - m); acc[t][j] = e; s += e; }
#pragma unroll
        for (int o = 1; o < 16; o <<= 1) s += __shfl_xor(s, o);
        const float rs = 1.f / s;
#pragma unroll
        for (int t = 0; t < 7; ++t) acc[t][j] *= rs;
    }
#pragma unroll
    for (int t = 0; t < 7; ++t)
#pragma unroll
        for (int j = 0; j < 4; ++j)
            addr[(size_t)(row0 + rb + j) * 896 + h * 112 + t * 16 + lr] = (__bf16)acc[t][j];
}

// ---------------- recon addressing: K=512, fused ||v_proj||, softmax -> addr2 [N,128] ----------------
__global__ __launch_bounds__(256) void recon_addr(const bf16_t* __restrict__ vp,
                                                  const bf16_t* __restrict__ mvb,
                                                  const float* __restrict__ invmv,
                                                  bf16_t* __restrict__ addr2) {
    const int wid = threadIdx.x >> 6, lane = threadIdx.x & 63;
    const int lr = lane & 15, kk = (lane >> 4) * 8;
    const int row0 = blockIdx.x * 64 + wid * 16;
    const bf16_t* a_ptr = vp + (size_t)(row0 + lr) * 512 + kk;
    f32x4 acc[7];
#pragma unroll
    for (int t = 0; t < 7; ++t) { acc[t][0] = 0.f; acc[t][1] = 0.f; acc[t][2] = 0.f; acc[t][3] = 0.f; }
    float ssq = 0.f;
    for (int k0 = 0; k0 < 512; k0 += 32) {
        bf16x8 a = *reinterpret_cast<const bf16x8*>(a_ptr + k0);
#pragma unroll
        for (int j = 0; j < 8; ++j) { float x = (float)a[j]; ssq += x * x; }
#pragma unroll
        for (int t = 0; t < 7; ++t) {
            bf16x8 b = *reinterpret_cast<const bf16x8*>(mvb + (size_t)(t * 16 + lr) * 512 + kk + k0);
            acc[t] = __builtin_amdgcn_mfma_f32_16x16x32_bf16(a, b, acc[t], 0, 0, 0);
        }
    }
    ssq += __shfl_xor(ssq, 16);
    ssq += __shfl_xor(ssq, 32);
    const float invq = 1.f / fmaxf(sqrtf(ssq), 1e-12f);
    const int rb = (lane >> 4) * 4;
    float iq[4];
#pragma unroll
    for (int j = 0; j < 4; ++j) iq[j] = __shfl(invq, rb + j);
    float imv_t[7];
#pragma unroll
    for (int t = 0; t < 7; ++t) imv_t[t] = invmv[t * 16 + lr];
#pragma unroll
    for (int j = 0; j < 4; ++j) {
        float m = -1e30f;
#pragma unroll
        for (int t = 0; t < 7; ++t) { acc[t][j] *= iq[j] * imv_t[t] * RADIUS_F; m = fmaxf(m, acc[t][j]); }
#pragma unroll
        for (int o = 1; o < 16; o <<= 1) m = fmaxf(m, __shfl_xor(m, o));
        float s = 0.f;
#pragma unroll
        for (int t = 0; t < 7; ++t) { float e = __expf(acc[t][j] - m); acc[t][j] = e; s += e; }
#pragma unroll
        for (int o = 1; o < 16; o <<= 1) s += __shfl_xor(s, o);
        const float rs = 1.f / s;
#pragma unroll
        for (int t = 0; t < 7; ++t) acc[t][j] *= rs;
    }
#pragma unroll
    for (int t = 0; t < 7; ++t)
#pragma unroll
        for (int j = 0; j < 4; ++j)
            addr2[(size_t)(row0 + rb + j) * 128 + t * 16 + lr] = (__bf16)acc[t][j];
#pragma unroll
    for (int j = 0; j < 4; ++j)
        addr2[(size_t)(row0 + rb + j) * 128 + 112 + lr] = (__bf16)0.f;
}

// ---------------- LN epilogues ----------------
// f_predict = LN1(query + attn_out), in place on io
__global__ __launch_bounds__(256) void ln_predict_k(float* __restrict__ io,
                                                    const float* __restrict__ query,
                                                    const float* __restrict__ g,
                                                    const float* __restrict__ b) {
    const int row = blockIdx.x, tid = threadIdx.x;
    const int i0 = tid * 2;
    const size_t base = (size_t)row * 512;
    float2 q = *reinterpret_cast<const float2*>(query + base + i0);
    float2 a = *reinterpret_cast<const float2*>(io + base + i0);
    float x0 = q.x + a.x, x1 = q.y + a.y;
    __shared__ float red[2][4];
    float s = wave_sum(x0 + x1);
    float s2 = wave_sum(x0 * x0 + x1 * x1);
    const int wid = tid >> 6, lane = tid & 63;
    if (lane == 0) { red[0][wid] = s; red[1][wid] = s2; }
    __syncthreads();
    s = red[0][0] + red[0][1] + red[0][2] + red[0][3];
    s2 = red[1][0] + red[1][1] + red[1][2] + red[1][3];
    const float m = s * (1.f / 512.f);
    const float r = rsqrtf(s2 * (1.f / 512.f) - m * m + LN_EPS);
    float2 o;
    o.x = (x0 - m) * r * g[i0] + b[i0];
    o.y = (x1 - m) * r * g[i0 + 1] + b[i0 + 1];
    *reinterpret_cast<float2*>(io + base + i0) = o;
}

// recon epilogue: cos-loss per row, LN3, +query, LN1 — in place on io (= attn_recon)
__global__ __launch_bounds__(256) void recon_ep_k(float* __restrict__ io,
                                                  const float* __restrict__ query,
                                                  const float* __restrict__ value,
                                                  const float* __restrict__ g3,
                                                  const float* __restrict__ b3,
                                                  const float* __restrict__ g1,
                                                  const float* __restrict__ b1,
                                                  float* __restrict__ rr) {
    const int row = blockIdx.x, tid = threadIdx.x;
    const int i0 = tid * 2;
    const size_t base = (size_t)row * 512;
    float2 a = *reinterpret_cast<const float2*>(io + base + i0);
    float2 v = *reinterpret_cast<const float2*>(value + base + i0);
    float2 q = *reinterpret_cast<const float2*>(query + base + i0);
    __shared__ float red[4][4];
    float sa = wave_sum(a.x + a.y);
    float sa2 = wave_sum(a.x * a.x + a.y * a.y);
    float sav = wave_sum(a.x * v.x + a.y * v.y);
    float sv2 = wave_sum(v.x * v.x + v.y * v.y);
    const int wid = tid >> 6, lane = tid & 63;
    if (lane == 0) { red[0][wid] = sa; red[1][wid] = sa2; red[2][wid] = sav; red[3][wid] = sv2; }
    __syncthreads();
    sa = red[0][0] + red[0][1] + red[0][2] + red[0][3];
    sa2 = red[1][0] + red[1][1] + red[1][2] + red[1][3];
    sav = red[2][0] + red[2][1] + red[2][2] + red[2][3];
    sv2 = red[3][0] + red[3][1] + red[3][2] + red[3][3];
    const float na = fmaxf(sqrtf(sa2), 1e-12f), nv = fmaxf(sqrtf(sv2), 1e-12f);
    if (tid == 0) rr[row] = fabsf(1.f - sav / (na * nv));
    const float m3 = sa * (1.f / 512.f);
    const float r3 = rsqrtf(sa2 * (1.f / 512.f) - m3 * m3 + LN_EPS);
    float x0 = q.x + (a.x - m3) * r3 * g3[i0] + b3[i0];
    float x1 = q.y + (a.y - m3) * r3 * g3[i0 + 1] + b3[i0 + 1];
    __syncthreads();
    float s = wave_sum(x0 + x1);
    float s2 = wave_sum(x0 * x0 + x1 * x1);
    if (lane == 0) { red[0][wid] = s; red[1][wid] = s2; }
    __syncthreads();
    s = red[0][0] + red[0][1] + red[0][2] + red[0][3];
    s2 = red[1][0] + red[1][1] + red[1][2] + red[1][3];
    const float m = s * (1.f / 512.f);
    const float r = rsqrtf(s2 * (1.f / 512.f) - m * m + LN_EPS);
    io[base + i0] = (x0 - m) * r * g1[i0] + b1[i0];
    io[base + i0 + 1] = (x1 - m) * r * g1[i0 + 1] + b1[i0 + 1];
}

__global__ __launch_bounds__(256) void reduce_rr_k(const float* __restrict__ rr,
                                                   float* __restrict__ out) {
    float s = 0.f;
    for (int i = threadIdx.x; i < 32768; i += 256) s += rr[i];
    s = wave_sum(s);
    __shared__ float red[4];
    const int wid = threadIdx.x >> 6, lane = threadIdx.x & 63;
    if (lane == 0) red[wid] = s;
    __syncthreads();
    if (threadIdx.x == 0) out[0] = (red[0] + red[1] + red[2] + red[3]) * (1.f / 32768.f);
}

extern "C" void kernel_launch(void* const* d_in, const int* in_sizes, int n_in,
                              void* d_out, int out_size, void* d_ws, size_t ws_size,
                              hipStream_t stream) {
    const float* query = (const float*)d_in[0];
    const float* value = (const float*)d_in[1];
    const float* mem_key = (const float*)d_in[2];
    const float* mem_value = (const float*)d_in[3];
    const float* q_w = (const float*)d_in[4];
    const float* q_b = (const float*)d_in[5];
    const float* v_w = (const float*)d_in[6];
    const float* v_b = (const float*)d_in[7];
    const float* out_w = (const float*)d_in[8];
    const float* out_b = (const float*)d_in[9];
    const float* ln1_g = (const float*)d_in[10];
    const float* ln1_b = (const float*)d_in[11];
    const float* ln3_g = (const float*)d_in[12];
    const float* ln3_b = (const float*)d_in[13];
    float* out = (float*)d_out;

    char* ws = (char*)d_ws;
    size_t off = 0;
    auto alloc = [&](size_t bytes) {
        void* p = ws + off;
        off += (bytes + 255) & ~(size_t)255;
        return p;
    };
    bf16_t* bufA = (bf16_t*)alloc(16777216ull * 2);  // query_bf16, then value_bf16
    bf16_t* bufB = (bf16_t*)alloc(16777216ull * 2);  // qp_bf16, then v_proj_bf16
    bf16_t* addr = (bf16_t*)alloc(32768ull * 896 * 2);  // addr, later addr2
    bf16_t* qwb = (bf16_t*)alloc(262144ull * 2);
    bf16_t* vwb = (bf16_t*)alloc(262144ull * 2);
    bf16_t* owb = (bf16_t*)alloc(2097152ull * 2);
    bf16_t* wct = (bf16_t*)alloc(896ull * 512 * 2);  // WcT[512][896]
    bf16_t* keyn = (bf16_t*)alloc(896ull * 64 * 2);
    bf16_t* mvb = (bf16_t*)alloc(112ull * 512 * 2);
    bf16_t* mvT = (bf16_t*)alloc(512ull * 128 * 2);
    float* invmv = (float*)alloc(112 * 4);
    float* rr = (float*)alloc(32768ull * 4);
    bf16_t* addr2 = addr;

    float* attn_out = out;                // f_predict slot (staging)
    float* attn_recon = out + 16777216;   // f_target_recon slot (staging)
    float* loss_slots = out + 33554432;   // [recon_loss, contrastive_loss]

    // prep
    cast_k<<<256, 256, 0, stream>>>(q_w, qwb, 65536);
    cast_k<<<256, 256, 0, stream>>>(v_w, vwb, 65536);
    cast_k<<<2048, 256, 0, stream>>>(out_w, owb, 524288);
    cast_k<<<16384, 256, 0, stream>>>(query, bufA, 4194304);
    keyn_k<<<224, 256, 0, stream>>>(mem_key, keyn);
    mv_prep_k<<<112, 256, 0, stream>>>(mem_value, mvb, invmv, loss_slots);
    mvT_k<<<256, 256, 0, stream>>>(mem_value, mvT);
    contrastive_k<<<112, 256, 0, stream>>>(mem_value, invmv, loss_slots + 1);
    // WcT[d][h*112+s] = sum_j out_w[d][h*512+j] * mem_value[s][j]
    gemm_bt<<<dim3(8, 2, 8), 256, 0, stream>>>(owb, 4096, 512, mvb, 512, 0,
                                               (const float*)nullptr,
                                               (float*)nullptr, wct, 896, 112,
                                               512, 112, 512);
    // predict branch
    gemm_bt<<<dim3(512, 8, 1), 256, 0, stream>>>(bufA, 512, 0, qwb, 512, 0, q_b,
                                                 (float*)nullptr, bufB, 512, 0,
                                                 32768, 512, 512);
    addr_predict<<<dim3(512, 8), 256, 0, stream>>>(bufB, keyn, addr);
    gemm_bt<<<dim3(512, 8, 1), 256, 0, stream>>>(addr, 896, 0, wct, 896, 0, out_b,
                                                 attn_out, (bf16_t*)nullptr, 512, 0,
                                                 32768, 512, 896);
    ln_predict_k<<<32768, 256, 0, stream>>>(attn_out, query, ln1_g, ln1_b);
    // recon branch
    cast_k<<<16384, 256, 0, stream>>>(value, bufA, 4194304);
    gemm_bt<<<dim3(512, 8, 1), 256, 0, stream>>>(bufA, 512, 0, vwb, 512, 0, v_b,
                                                 (float*)nullptr, bufB, 512, 0,
                                                 32768, 512, 512);
    recon_addr<<<512, 256, 0, stream>>>(bufB, mvb, invmv, addr2);
    gemm_bt<<<dim3(512, 8, 1), 256, 0, stream>>>(addr2, 128, 0, mvT, 128, 0,
                                                 (const float*)nullptr,
                                                 attn_recon, (bf16_t*)nullptr, 512, 0,
                                                 32768, 512, 128);
    recon_ep_k<<<32768, 256, 0, stream>>>(attn_recon, query, value, ln3_g, ln3_b,
                                          ln1_g, ln1_b, rr);
    reduce_rr_k<<<1, 256, 0, stream>>>(rr, loss_slots);
}

// Round 2
// 469.123 us; speedup vs baseline: 1.9182x; 1.9182x over previous
//
#include <hip/hip_runtime.h>
#include <hip/hip_bf16.h>
#include <math.h>

typedef __bf16 bf16_t;
typedef __attribute__((ext_vector_type(8))) __bf16 bf16x8;
typedef __attribute__((ext_vector_type(4))) __bf16 bf16x4;
typedef __attribute__((ext_vector_type(4))) float f32x4;

#define LN_EPS 1e-5f
#define RADIUS_F 16.0f

__device__ inline bf16x8 zero8() {
    bf16x8 v;
#pragma unroll
    for (int i = 0; i < 8; ++i) v[i] = (__bf16)0.f;
    return v;
}

__device__ inline float wave_sum(float v) {
#pragma unroll
    for (int o = 1; o < 64; o <<= 1) v += __shfl_xor(v, o);
    return v;
}

__device__ inline void gload_lds16(const bf16_t* g, bf16_t* l) {
    __builtin_amdgcn_global_load_lds(
        (const __attribute__((address_space(1))) void*)g,
        (__attribute__((address_space(3))) void*)l, 16, 0, 0);
}

// ---------------- casts ----------------
__global__ __launch_bounds__(256) void cast_k(const float* __restrict__ in,
                                              bf16_t* __restrict__ out, int n4) {
    int i = blockIdx.x * 256 + threadIdx.x;
    if (i < n4) {
        float4 v = reinterpret_cast<const float4*>(in)[i];
        bf16x4 o;
        o[0] = (__bf16)v.x; o[1] = (__bf16)v.y; o[2] = (__bf16)v.z; o[3] = (__bf16)v.w;
        reinterpret_cast<bf16x4*>(out)[i] = o;
    }
}

// normalize mem_key rows (896 x 64) -> bf16
__global__ __launch_bounds__(256) void keyn_k(const float* __restrict__ mk,
                                              bf16_t* __restrict__ kn) {
    int row = blockIdx.x * 4 + (threadIdx.x >> 6);
    int lane = threadIdx.x & 63;
    float x = mk[(size_t)row * 64 + lane];
    float ss = wave_sum(x * x);
    kn[(size_t)row * 64 + lane] = (__bf16)(x / fmaxf(sqrtf(ss), 1e-12f));
}

// mem_value: row inv-norms + bf16 copy (padded to 128 rows, zero tail);
// also zero the two loss slots
__global__ __launch_bounds__(256) void mv_prep_k(const float* __restrict__ mv,
                                                 bf16_t* __restrict__ mvb,
                                                 float* __restrict__ invmv,
                                                 float* __restrict__ loss_slots) {
    const int s = blockIdx.x, tid = threadIdx.x;
    if (s >= 112) {
        mvb[(size_t)s * 512 + tid * 2] = (__bf16)0.f;
        mvb[(size_t)s * 512 + tid * 2 + 1] = (__bf16)0.f;
        return;
    }
    float2 x = *reinterpret_cast<const float2*>(mv + (size_t)s * 512 + tid * 2);
    float ss = wave_sum(x.x * x.x + x.y * x.y);
    __shared__ float red[4];
    int wid = tid >> 6, lane = tid & 63;
    if (lane == 0) red[wid] = ss;
    __syncthreads();
    ss = red[0] + red[1] + red[2] + red[3];
    if (tid == 0) invmv[s] = 1.f / fmaxf(sqrtf(ss), 1e-12f);
    mvb[(size_t)s * 512 + tid * 2] = (__bf16)x.x;
    mvb[(size_t)s * 512 + tid * 2 + 1] = (__bf16)x.y;
    if (s == 0 && tid < 2) loss_slots[tid] = 0.f;
}

// mem_value transposed + zero-padded to [512][128] bf16
__global__ __launch_bounds__(256) void mvT_k(const float* __restrict__ mv,
                                             bf16_t* __restrict__ mvT) {
    int idx = blockIdx.x * 256 + threadIdx.x;  // 512*128
    int j = idx >> 7, s = idx & 127;
    mvT[idx] = (__bf16)(s < 112 ? mv[(size_t)s * 512 + j] : 0.f);
}

// contrastive loss: sum |I - Gn Gn^T| * 0.01  (fp32)
__global__ __launch_bounds__(256) void contrastive_k(const float* __restrict__ mv,
                                                     const float* __restrict__ invmv,
                                                     float* __restrict__ out_slot) {
    const int a = blockIdx.x;
    const int tid = threadIdx.x, wid = tid >> 6, lane = tid & 63;
    __shared__ float rowa[512];
    __shared__ float wsum[4];
    for (int i = tid; i < 512; i += 256) rowa[i] = mv[(size_t)a * 512 + i];
    __syncthreads();
    float acc = 0.f;
    const float ia = invmv[a];
    for (int b = wid; b < 112; b += 4) {
        float d = 0.f;
#pragma unroll
        for (int i = 0; i < 8; ++i) d += rowa[lane + i * 64] * mv[(size_t)b * 512 + lane + i * 64];
        d = wave_sum(d);
        float gv = d * ia * invmv[b];
        acc += fabsf((a == b ? 1.f : 0.f) - gv);
    }
    if (lane == 0) wsum[wid] = acc;
    __syncthreads();
    if (tid == 0) atomicAdd(out_slot, (wsum[0] + wsum[1] + wsum[2] + wsum[3]) * 0.01f);
}

// ---------------- 128x128-tile LDS-staged MFMA GEMM (m97 structure) ----------------
// C[M,N] = A[M,K](bf16,lda) * W[N,K]^T(bf16,ldw) (+bias[col])
// grid = (M/128, N/128). 256 threads = 4 waves in 2x2; BK=32, global_load_lds(16B).
__global__ __launch_bounds__(256) void gemm128(
    const bf16_t* __restrict__ A, int lda,
    const bf16_t* __restrict__ W, int ldw,
    const float* __restrict__ bias,
    float* __restrict__ Cf, bf16_t* __restrict__ Cb, int ldc,
    int K) {
    __shared__ __align__(16) bf16_t As[128 * 32];
    __shared__ __align__(16) bf16_t Bs[128 * 32];
    const int tid = threadIdx.x;
    const int wid = tid >> 6, lane = tid & 63;
    const int wr = wid >> 1, wc = wid & 1;
    const int lr = lane & 15;
    const int ko = (lane >> 4) * 8;
    const size_t rowBase = (size_t)blockIdx.x * 128;
    const size_t colBase = (size_t)blockIdx.y * 128;
    const int r0 = tid >> 2;         // staging row 0..63
    const int c0 = (tid & 3) * 8;    // staging k-offset (elements)
    const bf16_t* a_src = A + (rowBase + r0) * lda + c0;
    const bf16_t* w_src = W + (colBase + r0) * ldw + c0;
    f32x4 acc[4][4];
#pragma unroll
    for (int m = 0; m < 4; ++m)
#pragma unroll
        for (int n = 0; n < 4; ++n) {
            acc[m][n][0] = 0.f; acc[m][n][1] = 0.f;
            acc[m][n][2] = 0.f; acc[m][n][3] = 0.f;
        }
    for (int k0 = 0; k0 < K; k0 += 32) {
        __syncthreads();
        gload_lds16(a_src + k0, As + tid * 8);
        gload_lds16(a_src + (size_t)64 * lda + k0, As + 2048 + tid * 8);
        gload_lds16(w_src + k0, Bs + tid * 8);
        gload_lds16(w_src + (size_t)64 * ldw + k0, Bs + 2048 + tid * 8);
        __syncthreads();
        bf16x8 af[4], bfr[4];
#pragma unroll
        for (int m = 0; m < 4; ++m)
            af[m] = *reinterpret_cast<const bf16x8*>(As + (wr * 64 + m * 16 + lr) * 32 + ko);
#pragma unroll
        for (int n = 0; n < 4; ++n)
            bfr[n] = *reinterpret_cast<const bf16x8*>(Bs + (wc * 64 + n * 16 + lr) * 32 + ko);
#pragma unroll
        for (int m = 0; m < 4; ++m)
#pragma unroll
            for (int n = 0; n < 4; ++n)
                acc[m][n] = __builtin_amdgcn_mfma_f32_16x16x32_bf16(af[m], bfr[n], acc[m][n], 0, 0, 0);
    }
    const int rj = (lane >> 4) * 4;
#pragma unroll
    for (int n = 0; n < 4; ++n) {
        const int col = (int)colBase + wc * 64 + n * 16 + lr;
        const float bv = bias ? bias[col] : 0.f;
#pragma unroll
        for (int m = 0; m < 4; ++m) {
            const size_t r = rowBase + wr * 64 + m * 16 + rj;
#pragma unroll
            for (int j = 0; j < 4; ++j) {
                float v = acc[m][n][j] + bv;
                if (Cf) Cf[(r + j) * ldc + col] = v;
                else Cb[(r + j) * ldc + col] = (__bf16)v;
            }
        }
    }
}

// ---------------- small direct GEMM (kept for the 512x112 WcT fold only) ----------------
__global__ __launch_bounds__(256) void gemm_bt(
    const bf16_t* __restrict__ A, int lda, int aZ,
    const bf16_t* __restrict__ W, int ldw, int wZ,
    const float* __restrict__ bias,
    float* __restrict__ Cf, bf16_t* __restrict__ Cb, int ldc, int cZ,
    int M, int N, int K) {
    const int wid = threadIdx.x >> 6;
    const int lane = threadIdx.x & 63;
    const int lr = lane & 15;
    const int kk = (lane >> 4) * 8;
    const int row0 = blockIdx.x * 64 + wid * 16;
    const int col0 = blockIdx.y * 64;
    A += (size_t)blockIdx.z * aZ;
    W += (size_t)blockIdx.z * wZ;
    const bf16_t* a_ptr = A + (size_t)(row0 + lr) * lda + kk;
    const bf16_t* w_ptr = W + (size_t)(col0 + lr) * ldw + kk;
    f32x4 acc[4];
#pragma unroll
    for (int t = 0; t < 4; ++t) { acc[t][0] = 0.f; acc[t][1] = 0.f; acc[t][2] = 0.f; acc[t][3] = 0.f; }
    bool colv[4];
#pragma unroll
    for (int t = 0; t < 4; ++t) colv[t] = (col0 + t * 16 + lr) < N;
    for (int k0 = 0; k0 < K; k0 += 32) {
        bf16x8 a = *reinterpret_cast<const bf16x8*>(a_ptr + k0);
#pragma unroll
        for (int t = 0; t < 4; ++t) {
            bf16x8 b;
            if (colv[t]) b = *reinterpret_cast<const bf16x8*>(w_ptr + (size_t)t * 16 * ldw + k0);
            else b = zero8();
            acc[t] = __builtin_amdgcn_mfma_f32_16x16x32_bf16(a, b, acc[t], 0, 0, 0);
        }
    }
    const int rb = (lane >> 4) * 4;
    if (Cf) Cf += (size_t)blockIdx.z * cZ;
    if (Cb) Cb += (size_t)blockIdx.z * cZ;
#pragma unroll
    for (int t = 0; t < 4; ++t) {
        int col = col0 + t * 16 + lr;
        if (col >= N) continue;
        float bv = bias ? bias[col] : 0.f;
#pragma unroll
        for (int j = 0; j < 4; ++j) {
            int r = row0 + rb + j;
            float v = acc[t][j] + bv;
            if (Cf) Cf[(size_t)r * ldc + col] = v;
            else Cb[(size_t)r * ldc + col] = (__bf16)v;
        }
    }
}

// ---------------- predict addressing: sim -> softmax -> addr bf16 [N,896] ----------------
__global__ __launch_bounds__(256) void addr_predict(const bf16_t* __restrict__ qp,
                                                    const bf16_t* __restrict__ keyn,
                                                    bf16_t* __restrict__ addr) {
    const int wid = threadIdx.x >> 6, lane = threadIdx.x & 63;
    const int lr = lane & 15, kk = (lane >> 4) * 8;
    const int h = blockIdx.y;
    const int row0 = blockIdx.x * 64 + wid * 16;
    const bf16_t* a_ptr = qp + (size_t)(row0 + lr) * 512 + h * 64 + kk;
    bf16x8 a0 = *reinterpret_cast<const bf16x8*>(a_ptr);
    bf16x8 a1 = *reinterpret_cast<const bf16x8*>(a_ptr + 32);
    float ssq = 0.f;
#pragma unroll
    for (int j = 0; j < 8; ++j) {
        float x = (float)a0[j], y = (float)a1[j];
        ssq += x * x + y * y;
    }
    ssq += __shfl_xor(ssq, 16);
    ssq += __shfl_xor(ssq, 32);
    const float invq = 1.f / fmaxf(sqrtf(ssq), 1e-12f);
    f32x4 acc[7];
#pragma unroll
    for (int t = 0; t < 7; ++t) {
        const bf16_t* b_ptr = keyn + (size_t)(h * 112 + t * 16 + lr) * 64 + kk;
        bf16x8 b0 = *reinterpret_cast<const bf16x8*>(b_ptr);
        bf16x8 b1 = *reinterpret_cast<const bf16x8*>(b_ptr + 32);
        f32x4 c; c[0] = 0.f; c[1] = 0.f; c[2] = 0.f; c[3] = 0.f;
        c = __builtin_amdgcn_mfma_f32_16x16x32_bf16(a0, b0, c, 0, 0, 0);
        c = __builtin_amdgcn_mfma_f32_16x16x32_bf16(a1, b1, c, 0, 0, 0);
        acc[t] = c;
    }
    const int rb = (lane >> 4) * 4;
    float iq[4];
#pragma unroll
    for (int j = 0; j < 4; ++j) iq[j] = __shfl(invq, rb + j);
#pragma unroll
    for (int j = 0; j < 4; ++j) {
        float m = -1e30f;
#pragma unroll
        for (int t = 0; t < 7; ++t) { acc[t][j] *= iq[j] * RADIUS_F; m = fmaxf(m, acc[t][j]); }
#pragma unroll
        for (int o = 1; o < 16; o <<= 1) m = fmaxf(m, __shfl_xor(m, o));
        float s = 0.f;
#pragma unroll
        for (int t = 0; t < 7; ++t) { float e = __expf(acc[t][j] - m); acc[t][j] = e; s += e; }
#pragma unroll
        for (int o = 1; o < 16; o <<= 1) s += __shfl_xor(s, o);
        const float rs = 1.f / s;
#pragma unroll
        for (int t = 0; t < 7; ++t) acc[t][j] *= rs;
    }
#pragma unroll
    for (int t = 0; t < 7; ++t)
#pragma unroll
        for (int j = 0; j < 4; ++j)
            addr[(size_t)(row0 + rb + j) * 896 + h * 112 + t * 16 + lr] = (__bf16)acc[t][j];
}

// ---------------- recon softmax: one wave per row over 112 slots ----------------
// x = sim * inv||vp_row|| * inv||mv_slot|| * R ; addr2 = softmax(x), padded to 128
__global__ __launch_bounds__(256) void recon_softmax(const bf16_t* __restrict__ vp,
                                                     const float* __restrict__ sim,
                                                     const float* __restrict__ invmv,
                                                     bf16_t* __restrict__ addr2) {
    const int wid = threadIdx.x >> 6, lane = threadIdx.x & 63;
    const size_t row = (size_t)blockIdx.x * 4 + wid;
    bf16x8 v = *reinterpret_cast<const bf16x8*>(vp + row * 512 + lane * 8);
    float ssq = 0.f;
#pragma unroll
    for (int j = 0; j < 8; ++j) { float x = (float)v[j]; ssq += x * x; }
    ssq = wave_sum(ssq);
    const float invq = 1.f / fmaxf(sqrtf(ssq), 1e-12f);
    float x0 = sim[row * 128 + lane] * invq * invmv[lane] * RADIUS_F;
    float x1 = (lane < 48) ? sim[row * 128 + 64 + lane] * invq * invmv[64 + lane] * RADIUS_F
                           : -1e30f;
    float m = fmaxf(x0, x1);
#pragma unroll
    for (int o = 1; o < 64; o <<= 1) m = fmaxf(m, __shfl_xor(m, o));
    float e0 = __expf(x0 - m);
    float e1 = (lane < 48) ? __expf(x1 - m) : 0.f;
    float s = wave_sum(e0 + e1);
    const float rs = 1.f / s;
    addr2[row * 128 + lane] = (__bf16)(e0 * rs);
    addr2[row * 128 + 64 + lane] = (__bf16)(lane < 48 ? e1 * rs : 0.f);
}

// ---------------- LN epilogues ----------------
__global__ __launch_bounds__(256) void ln_predict_k(float* __restrict__ io,
                                                    const float* __restrict__ query,
                                                    const float* __restrict__ g,
                                                    const float* __restrict__ b) {
    const int row = blockIdx.x, tid = threadIdx.x;
    const int i0 = tid * 2;
    const size_t base = (size_t)row * 512;
    float2 q = *reinterpret_cast<const float2*>(query + base + i0);
    float2 a = *reinterpret_cast<const float2*>(io + base + i0);
    float x0 = q.x + a.x, x1 = q.y + a.y;
    __shared__ float red[2][4];
    float s = wave_sum(x0 + x1);
    float s2 = wave_sum(x0 * x0 + x1 * x1);
    const int wid = tid >> 6, lane = tid & 63;
    if (lane == 0) { red[0][wid] = s; red[1][wid] = s2; }
    __syncthreads();
    s = red[0][0] + red[0][1] + red[0][2] + red[0][3];
    s2 = red[1][0] + red[1][1] + red[1][2] + red[1][3];
    const float m = s * (1.f / 512.f);
    const float r = rsqrtf(s2 * (1.f / 512.f) - m * m + LN_EPS);
    float2 o;
    o.x = (x0 - m) * r * g[i0] + b[i0];
    o.y = (x1 - m) * r * g[i0 + 1] + b[i0 + 1];
    *reinterpret_cast<float2*>(io + base + i0) = o;
}

__global__ __launch_bounds__(256) void recon_ep_k(float* __restrict__ io,
                                                  const float* __restrict__ query,
                                                  const float* __restrict__ value,
                                                  const float* __restrict__ g3,
                                                  const float* __restrict__ b3,
                                                  const float* __restrict__ g1,
                                                  const float* __restrict__ b1,
                                                  float* __restrict__ rr) {
    const int row = blockIdx.x, tid = threadIdx.x;
    const int i0 = tid * 2;
    const size_t base = (size_t)row * 512;
    float2 a = *reinterpret_cast<const float2*>(io + base + i0);
    float2 v = *reinterpret_cast<const float2*>(value + base + i0);
    float2 q = *reinterpret_cast<const float2*>(query + base + i0);
    __shared__ float red[4][4];
    float sa = wave_sum(a.x + a.y);
    float sa2 = wave_sum(a.x * a.x + a.y * a.y);
    float sav = wave_sum(a.x * v.x + a.y * v.y);
    float sv2 = wave_sum(v.x * v.x + v.y * v.y);
    const int wid = tid >> 6, lane = tid & 63;
    if (lane == 0) { red[0][wid] = sa; red[1][wid] = sa2; red[2][wid] = sav; red[3][wid] = sv2; }
    __syncthreads();
    sa = red[0][0] + red[0][1] + red[0][2] + red[0][3];
    sa2 = red[1][0] + red[1][1] + red[1][2] + red[1][3];
    sav = red[2][0] + red[2][1] + red[2][2] + red[2][3];
    sv2 = red[3][0] + red[3][1] + red[3][2] + red[3][3];
    const float na = fmaxf(sqrtf(sa2), 1e-12f), nv = fmaxf(sqrtf(sv2), 1e-12f);
    if (tid == 0) rr[row] = fabsf(1.f - sav / (na * nv));
    const float m3 = sa * (1.f / 512.f);
    const float r3 = rsqrtf(sa2 * (1.f / 512.f) - m3 * m3 + LN_EPS);
    float x0 = q.x + (a.x - m3) * r3 * g3[i0] + b3[i0];
    float x1 = q.y + (a.y - m3) * r3 * g3[i0 + 1] + b3[i0 + 1];
    __syncthreads();
    float s = wave_sum(x0 + x1);
    float s2 = wave_sum(x0 * x0 + x1 * x1);
    if (lane == 0) { red[0][wid] = s; red[1][wid] = s2; }
    __syncthreads();
    s = red[0][0] + red[0][1] + red[0][2] + red[0][3];
    s2 = red[1][0] + red[1][1] + red[1][2] + red[1][3];
    const float m = s * (1.f / 512.f);
    const float r = rsqrtf(s2 * (1.f / 512.f) - m * m + LN_EPS);
    io[base + i0] = (x0 - m) * r * g1[i0] + b1[i0];
    io[base + i0 + 1] = (x1 - m) * r * g1[i0 + 1] + b1[i0 + 1];
}

__global__ __launch_bounds__(256) void reduce_rr_k(const float* __restrict__ rr,
                                                   float* __restrict__ out) {
    float s = 0.f;
    for (int i = threadIdx.x; i < 32768; i += 256) s += rr[i];
    s = wave_sum(s);
    __shared__ float red[4];
    const int wid = threadIdx.x >> 6, lane = threadIdx.x & 63;
    if (lane == 0) red[wid] = s;
    __syncthreads();
    if (threadIdx.x == 0) out[0] = (red[0] + red[1] + red[2] + red[3]) * (1.f / 32768.f);
}

extern "C" void kernel_launch(void* const* d_in, const int* in_sizes, int n_in,
                              void* d_out, int out_size, void* d_ws, size_t ws_size,
                              hipStream_t stream) {
    const float* query = (const float*)d_in[0];
    const float* value = (const float*)d_in[1];
    const float* mem_key = (const float*)d_in[2];
    const float* mem_value = (const float*)d_in[3];
    const float* q_w = (const float*)d_in[4];
    const float* q_b = (const float*)d_in[5];
    const float* v_w = (const float*)d_in[6];
    const float* v_b = (const float*)d_in[7];
    const float* out_w = (const float*)d_in[8];
    const float* out_b = (const float*)d_in[9];
    const float* ln1_g = (const float*)d_in[10];
    const float* ln1_b = (const float*)d_in[11];
    const float* ln3_g = (const float*)d_in[12];
    const float* ln3_b = (const float*)d_in[13];
    float* out = (float*)d_out;

    char* ws = (char*)d_ws;
    size_t off = 0;
    auto alloc = [&](size_t bytes) {
        void* p = ws + off;
        off += (bytes + 255) & ~(size_t)255;
        return p;
    };
    bf16_t* bufA = (bf16_t*)alloc(16777216ull * 2);   // query_bf16, then value_bf16
    bf16_t* bufB = (bf16_t*)alloc(16777216ull * 2);   // qp_bf16, then v_proj_bf16
    bf16_t* addr = (bf16_t*)alloc(32768ull * 896 * 2); // addr, later addr2
    float* sim = (float*)alloc(32768ull * 128 * 4);   // recon sim (fp32, ldc=128)
    bf16_t* qwb = (bf16_t*)alloc(262144ull * 2);
    bf16_t* vwb = (bf16_t*)alloc(262144ull * 2);
    bf16_t* owb = (bf16_t*)alloc(2097152ull * 2);
    bf16_t* wct = (bf16_t*)alloc(896ull * 512 * 2);   // WcT[512][896]
    bf16_t* keyn = (bf16_t*)alloc(896ull * 64 * 2);
    bf16_t* mvb = (bf16_t*)alloc(128ull * 512 * 2);   // padded to 128 rows
    bf16_t* mvT = (bf16_t*)alloc(512ull * 128 * 2);
    float* invmv = (float*)alloc(112 * 4);
    float* rr = (float*)alloc(32768ull * 4);
    bf16_t* addr2 = addr;

    float* attn_out = out;                // f_predict slot (staging)
    float* attn_recon = out + 16777216;   // f_target_recon slot (staging)
    float* loss_slots = out + 33554432;   // [recon_loss, contrastive_loss]

    // prep
    cast_k<<<256, 256, 0, stream>>>(q_w, qwb, 65536);
    cast_k<<<256, 256, 0, stream>>>(v_w, vwb, 65536);
    cast_k<<<2048, 256, 0, stream>>>(out_w, owb, 524288);
    cast_k<<<16384, 256, 0, stream>>>(query, bufA, 4194304);
    keyn_k<<<224, 256, 0, stream>>>(mem_key, keyn);
    mv_prep_k<<<128, 256, 0, stream>>>(mem_value, mvb, invmv, loss_slots);
    mvT_k<<<256, 256, 0, stream>>>(mem_value, mvT);
    contrastive_k<<<112, 256, 0, stream>>>(mem_value, invmv, loss_slots + 1);
    // WcT[d][h*112+s] = sum_j out_w[d][h*512+j] * mem_value[s][j]
    gemm_bt<<<dim3(8, 2, 8), 256, 0, stream>>>(owb, 4096, 512, mvb, 512, 0,
                                               (const float*)nullptr,
                                               (float*)nullptr, wct, 896, 112,
                                               512, 112, 512);
    // predict branch
    gemm128<<<dim3(256, 4), 256, 0, stream>>>(bufA, 512, qwb, 512, q_b,
                                              (float*)nullptr, bufB, 512, 512);
    addr_predict<<<dim3(512, 8), 256, 0, stream>>>(bufB, keyn, addr);
    gemm128<<<dim3(256, 4), 256, 0, stream>>>(addr, 896, wct, 896, out_b,
                                              attn_out, (bf16_t*)nullptr, 512, 896);
    ln_predict_k<<<32768, 256, 0, stream>>>(attn_out, query, ln1_g, ln1_b);
    // recon branch
    cast_k<<<16384, 256, 0, stream>>>(value, bufA, 4194304);
    gemm128<<<dim3(256, 4), 256, 0, stream>>>(bufA, 512, vwb, 512, v_b,
                                              (float*)nullptr, bufB, 512, 512);
    gemm128<<<dim3(256, 1), 256, 0, stream>>>(bufB, 512, mvb, 512,
                                              (const float*)nullptr,
                                              sim, (bf16_t*)nullptr, 128, 512);
    recon_softmax<<<8192, 256, 0, stream>>>(bufB, sim, invmv, addr2);
    gemm128<<<dim3(256, 4), 256, 0, stream>>>(addr2, 128, mvT, 128,
                                              (const float*)nullptr,
                                              attn_recon, (bf16_t*)nullptr, 512, 128);
    recon_ep_k<<<32768, 256, 0, stream>>>(attn_recon, query, value, ln3_g, ln3_b,
                                          ln1_g, ln1_b, rr);
    reduce_rr_k<<<1, 256, 0, stream>>>(rr, loss_slots);
}

// Round 3
// 371.409 us; speedup vs baseline: 2.4229x; 1.2631x over previous
//
#include <hip/hip_runtime.h>
#include <hip/hip_bf16.h>
#include <math.h>

typedef __bf16 bf16_t;
typedef __attribute__((ext_vector_type(8))) __bf16 bf16x8;
typedef __attribute__((ext_vector_type(4))) __bf16 bf16x4;
typedef __attribute__((ext_vector_type(4))) float f32x4;

#define LN_EPS 1e-5f
#define RADIUS_F 16.0f

__device__ inline bf16x8 zero8() {
    bf16x8 v;
#pragma unroll
    for (int i = 0; i < 8; ++i) v[i] = (__bf16)0.f;
    return v;
}

__device__ inline float wave_sum(float v) {
#pragma unroll
    for (int o = 1; o < 64; o <<= 1) v += __shfl_xor(v, o);
    return v;
}

__device__ inline void gload_lds16(const bf16_t* g, bf16_t* l) {
    __builtin_amdgcn_global_load_lds(
        (const __attribute__((address_space(1))) void*)g,
        (__attribute__((address_space(3))) void*)l, 16, 0, 0);
}

// ---------------- casts (weights only) ----------------
__global__ __launch_bounds__(256) void cast_k(const float* __restrict__ in,
                                              bf16_t* __restrict__ out, int n4) {
    int i = blockIdx.x * 256 + threadIdx.x;
    if (i < n4) {
        float4 v = reinterpret_cast<const float4*>(in)[i];
        bf16x4 o;
        o[0] = (__bf16)v.x; o[1] = (__bf16)v.y; o[2] = (__bf16)v.z; o[3] = (__bf16)v.w;
        reinterpret_cast<bf16x4*>(out)[i] = o;
    }
}

// normalize mem_key rows (896 x 64) -> bf16
__global__ __launch_bounds__(256) void keyn_k(const float* __restrict__ mk,
                                              bf16_t* __restrict__ kn) {
    int row = blockIdx.x * 4 + (threadIdx.x >> 6);
    int lane = threadIdx.x & 63;
    float x = mk[(size_t)row * 64 + lane];
    float ss = wave_sum(x * x);
    kn[(size_t)row * 64 + lane] = (__bf16)(x / fmaxf(sqrtf(ss), 1e-12f));
}

// mem_value: row inv-norms + bf16 copy (padded to 128 rows); zero loss slots
__global__ __launch_bounds__(256) void mv_prep_k(const float* __restrict__ mv,
                                                 bf16_t* __restrict__ mvb,
                                                 float* __restrict__ invmv,
                                                 float* __restrict__ loss_slots) {
    const int s = blockIdx.x, tid = threadIdx.x;
    if (s >= 112) {
        mvb[(size_t)s * 512 + tid * 2] = (__bf16)0.f;
        mvb[(size_t)s * 512 + tid * 2 + 1] = (__bf16)0.f;
        return;
    }
    float2 x = *reinterpret_cast<const float2*>(mv + (size_t)s * 512 + tid * 2);
    float ss = wave_sum(x.x * x.x + x.y * x.y);
    __shared__ float red[4];
    int wid = tid >> 6, lane = tid & 63;
    if (lane == 0) red[wid] = ss;
    __syncthreads();
    ss = red[0] + red[1] + red[2] + red[3];
    if (tid == 0) invmv[s] = 1.f / fmaxf(sqrtf(ss), 1e-12f);
    mvb[(size_t)s * 512 + tid * 2] = (__bf16)x.x;
    mvb[(size_t)s * 512 + tid * 2 + 1] = (__bf16)x.y;
    if (s == 0 && tid < 2) loss_slots[tid] = 0.f;
}

// mem_value transposed + zero-padded to [512][128] bf16
__global__ __launch_bounds__(256) void mvT_k(const float* __restrict__ mv,
                                             bf16_t* __restrict__ mvT) {
    int idx = blockIdx.x * 256 + threadIdx.x;  // 512*128
    int j = idx >> 7, s = idx & 127;
    mvT[idx] = (__bf16)(s < 112 ? mv[(size_t)s * 512 + j] : 0.f);
}

// contrastive loss: sum |I - Gn Gn^T| * 0.01  (fp32)
__global__ __launch_bounds__(256) void contrastive_k(const float* __restrict__ mv,
                                                     const float* __restrict__ invmv,
                                                     float* __restrict__ out_slot) {
    const int a = blockIdx.x;
    const int tid = threadIdx.x, wid = tid >> 6, lane = tid & 63;
    __shared__ float rowa[512];
    __shared__ float wsum[4];
    for (int i = tid; i < 512; i += 256) rowa[i] = mv[(size_t)a * 512 + i];
    __syncthreads();
    float acc = 0.f;
    const float ia = invmv[a];
    for (int b = wid; b < 112; b += 4) {
        float d = 0.f;
#pragma unroll
        for (int i = 0; i < 8; ++i) d += rowa[lane + i * 64] * mv[(size_t)b * 512 + lane + i * 64];
        d = wave_sum(d);
        float gv = d * ia * invmv[b];
        acc += fabsf((a == b ? 1.f : 0.f) - gv);
    }
    if (lane == 0) wsum[wid] = acc;
    __syncthreads();
    if (tid == 0) atomicAdd(out_slot, (wsum[0] + wsum[1] + wsum[2] + wsum[3]) * 0.01f);
}

// ---------------- 128x128 LDS-staged GEMM, A = fp32 (reg-staged + cvt) ----------------
// C[M,N](bf16) = A[M,K](fp32) * W[N,K]^T(bf16) + bias; grid = (M/128, N/128)
__global__ __launch_bounds__(256) void gemm128_f32a(
    const float* __restrict__ A, int lda,
    const bf16_t* __restrict__ W, int ldw,
    const float* __restrict__ bias,
    bf16_t* __restrict__ Cb, int ldc, int K) {
    __shared__ __align__(16) bf16_t As[128 * 32];
    __shared__ __align__(16) bf16_t Bs[128 * 32];
    const int tid = threadIdx.x;
    const int wid = tid >> 6, lane = tid & 63;
    const int wr = wid >> 1, wc = wid & 1;
    const int lr = lane & 15;
    const int ko = (lane >> 4) * 8;
    const size_t rowBase = (size_t)blockIdx.x * 128;
    const size_t colBase = (size_t)blockIdx.y * 128;
    const int r0 = tid >> 2;
    const int c0 = (tid & 3) * 8;
    const float* a_src = A + (rowBase + r0) * lda + c0;
    const bf16_t* w_src = W + (colBase + r0) * ldw + c0;
    f32x4 acc[4][4];
#pragma unroll
    for (int m = 0; m < 4; ++m)
#pragma unroll
        for (int n = 0; n < 4; ++n) {
            acc[m][n][0] = 0.f; acc[m][n][1] = 0.f;
            acc[m][n][2] = 0.f; acc[m][n][3] = 0.f;
        }
    for (int k0 = 0; k0 < K; k0 += 32) {
        float4 a0 = *reinterpret_cast<const float4*>(a_src + k0);
        float4 a1 = *reinterpret_cast<const float4*>(a_src + k0 + 4);
        float4 a2 = *reinterpret_cast<const float4*>(a_src + (size_t)64 * lda + k0);
        float4 a3 = *reinterpret_cast<const float4*>(a_src + (size_t)64 * lda + k0 + 4);
        __syncthreads();
        gload_lds16(w_src + k0, Bs + tid * 8);
        gload_lds16(w_src + (size_t)64 * ldw + k0, Bs + 2048 + tid * 8);
        bf16x8 p0, p1;
        p0[0] = (__bf16)a0.x; p0[1] = (__bf16)a0.y; p0[2] = (__bf16)a0.z; p0[3] = (__bf16)a0.w;
        p0[4] = (__bf16)a1.x; p0[5] = (__bf16)a1.y; p0[6] = (__bf16)a1.z; p0[7] = (__bf16)a1.w;
        p1[0] = (__bf16)a2.x; p1[1] = (__bf16)a2.y; p1[2] = (__bf16)a2.z; p1[3] = (__bf16)a2.w;
        p1[4] = (__bf16)a3.x; p1[5] = (__bf16)a3.y; p1[6] = (__bf16)a3.z; p1[7] = (__bf16)a3.w;
        *reinterpret_cast<bf16x8*>(As + tid * 8) = p0;
        *reinterpret_cast<bf16x8*>(As + 2048 + tid * 8) = p1;
        __syncthreads();
        bf16x8 af[4], bfr[4];
#pragma unroll
        for (int m = 0; m < 4; ++m)
            af[m] = *reinterpret_cast<const bf16x8*>(As + (wr * 64 + m * 16 + lr) * 32 + ko);
#pragma unroll
        for (int n = 0; n < 4; ++n)
            bfr[n] = *reinterpret_cast<const bf16x8*>(Bs + (wc * 64 + n * 16 + lr) * 32 + ko);
#pragma unroll
        for (int m = 0; m < 4; ++m)
#pragma unroll
            for (int n = 0; n < 4; ++n)
                acc[m][n] = __builtin_amdgcn_mfma_f32_16x16x32_bf16(af[m], bfr[n], acc[m][n], 0, 0, 0);
    }
    const int rj = (lane >> 4) * 4;
#pragma unroll
    for (int n = 0; n < 4; ++n) {
        const int col = (int)colBase + wc * 64 + n * 16 + lr;
        const float bv = bias ? bias[col] : 0.f;
#pragma unroll
        for (int m = 0; m < 4; ++m) {
            const size_t r = rowBase + wr * 64 + m * 16 + rj;
#pragma unroll
            for (int j = 0; j < 4; ++j)
                Cb[(r + j) * ldc + col] = (__bf16)(acc[m][n][j] + bv);
        }
    }
}

// ---------------- 128x128 LDS-staged GEMM, bf16 A (used for sim) ----------------
__global__ __launch_bounds__(256) void gemm128(
    const bf16_t* __restrict__ A, int lda,
    const bf16_t* __restrict__ W, int ldw,
    float* __restrict__ Cf, int ldc, int K) {
    __shared__ __align__(16) bf16_t As[128 * 32];
    __shared__ __align__(16) bf16_t Bs[128 * 32];
    const int tid = threadIdx.x;
    const int wid = tid >> 6, lane = tid & 63;
    const int wr = wid >> 1, wc = wid & 1;
    const int lr = lane & 15;
    const int ko = (lane >> 4) * 8;
    const size_t rowBase = (size_t)blockIdx.x * 128;
    const size_t colBase = (size_t)blockIdx.y * 128;
    const int r0 = tid >> 2;
    const int c0 = (tid & 3) * 8;
    const bf16_t* a_src = A + (rowBase + r0) * lda + c0;
    const bf16_t* w_src = W + (colBase + r0) * ldw + c0;
    f32x4 acc[4][4];
#pragma unroll
    for (int m = 0; m < 4; ++m)
#pragma unroll
        for (int n = 0; n < 4; ++n) {
            acc[m][n][0] = 0.f; acc[m][n][1] = 0.f;
            acc[m][n][2] = 0.f; acc[m][n][3] = 0.f;
        }
    for (int k0 = 0; k0 < K; k0 += 32) {
        __syncthreads();
        gload_lds16(a_src + k0, As + tid * 8);
        gload_lds16(a_src + (size_t)64 * lda + k0, As + 2048 + tid * 8);
        gload_lds16(w_src + k0, Bs + tid * 8);
        gload_lds16(w_src + (size_t)64 * ldw + k0, Bs + 2048 + tid * 8);
        __syncthreads();
        bf16x8 af[4], bfr[4];
#pragma unroll
        for (int m = 0; m < 4; ++m)
            af[m] = *reinterpret_cast<const bf16x8*>(As + (wr * 64 + m * 16 + lr) * 32 + ko);
#pragma unroll
        for (int n = 0; n < 4; ++n)
            bfr[n] = *reinterpret_cast<const bf16x8*>(Bs + (wc * 64 + n * 16 + lr) * 32 + ko);
#pragma unroll
        for (int m = 0; m < 4; ++m)
#pragma unroll
            for (int n = 0; n < 4; ++n)
                acc[m][n] = __builtin_amdgcn_mfma_f32_16x16x32_bf16(af[m], bfr[n], acc[m][n], 0, 0, 0);
    }
    const int rj = (lane >> 4) * 4;
#pragma unroll
    for (int n = 0; n < 4; ++n) {
        const int col = (int)colBase + wc * 64 + n * 16 + lr;
#pragma unroll
        for (int m = 0; m < 4; ++m) {
            const size_t r = rowBase + wr * 64 + m * 16 + rj;
#pragma unroll
            for (int j = 0; j < 4; ++j)
                Cf[(r + j) * ldc + col] = acc[m][n][j];
        }
    }
}

// ---------------- small direct GEMM (WcT fold only) ----------------
__global__ __launch_bounds__(256) void gemm_bt(
    const bf16_t* __restrict__ A, int lda, int aZ,
    const bf16_t* __restrict__ W, int ldw, int wZ,
    bf16_t* __restrict__ Cb, int ldc, int cZ,
    int M, int N, int K) {
    const int wid = threadIdx.x >> 6;
    const int lane = threadIdx.x & 63;
    const int lr = lane & 15;
    const int kk = (lane >> 4) * 8;
    const int row0 = blockIdx.x * 64 + wid * 16;
    const int col0 = blockIdx.y * 64;
    A += (size_t)blockIdx.z * aZ;
    W += (size_t)blockIdx.z * wZ;
    const bf16_t* a_ptr = A + (size_t)(row0 + lr) * lda + kk;
    const bf16_t* w_ptr = W + (size_t)(col0 + lr) * ldw + kk;
    f32x4 acc[4];
#pragma unroll
    for (int t = 0; t < 4; ++t) { acc[t][0] = 0.f; acc[t][1] = 0.f; acc[t][2] = 0.f; acc[t][3] = 0.f; }
    bool colv[4];
#pragma unroll
    for (int t = 0; t < 4; ++t) colv[t] = (col0 + t * 16 + lr) < N;
    for (int k0 = 0; k0 < K; k0 += 32) {
        bf16x8 a = *reinterpret_cast<const bf16x8*>(a_ptr + k0);
#pragma unroll
        for (int t = 0; t < 4; ++t) {
            bf16x8 b;
            if (colv[t]) b = *reinterpret_cast<const bf16x8*>(w_ptr + (size_t)t * 16 * ldw + k0);
            else b = zero8();
            acc[t] = __builtin_amdgcn_mfma_f32_16x16x32_bf16(a, b, acc[t], 0, 0, 0);
        }
    }
    const int rb = (lane >> 4) * 4;
    Cb += (size_t)blockIdx.z * cZ;
#pragma unroll
    for (int t = 0; t < 4; ++t) {
        int col = col0 + t * 16 + lr;
        if (col >= N) continue;
#pragma unroll
        for (int j = 0; j < 4; ++j) {
            int r = row0 + rb + j;
            Cb[(size_t)r * ldc + col] = (__bf16)acc[t][j];
        }
    }
}

// ---------------- predict addressing: sim -> softmax -> addr bf16 [N,896] ----------------
__global__ __launch_bounds__(256) void addr_predict(const bf16_t* __restrict__ qp,
                                                    const bf16_t* __restrict__ keyn,
                                                    bf16_t* __restrict__ addr) {
    const int wid = threadIdx.x >> 6, lane = threadIdx.x & 63;
    const int lr = lane & 15, kk = (lane >> 4) * 8;
    const int h = blockIdx.y;
    const int row0 = blockIdx.x * 64 + wid * 16;
    const bf16_t* a_ptr = qp + (size_t)(row0 + lr) * 512 + h * 64 + kk;
    bf16x8 a0 = *reinterpret_cast<const bf16x8*>(a_ptr);
    bf16x8 a1 = *reinterpret_cast<const bf16x8*>(a_ptr + 32);
    float ssq = 0.f;
#pragma unroll
    for (int j = 0; j < 8; ++j) {
        float x = (float)a0[j], y = (float)a1[j];
        ssq += x * x + y * y;
    }
    ssq += __shfl_xor(ssq, 16);
    ssq += __shfl_xor(ssq, 32);
    const float invq = 1.f / fmaxf(sqrtf(ssq), 1e-12f);
    f32x4 acc[7];
#pragma unroll
    for (int t = 0; t < 7; ++t) {
        const bf16_t* b_ptr = keyn + (size_t)(h * 112 + t * 16 + lr) * 64 + kk;
        bf16x8 b0 = *reinterpret_cast<const bf16x8*>(b_ptr);
        bf16x8 b1 = *reinterpret_cast<const bf16x8*>(b_ptr + 32);
        f32x4 c; c[0] = 0.f; c[1] = 0.f; c[2] = 0.f; c[3] = 0.f;
        c = __builtin_amdgcn_mfma_f32_16x16x32_bf16(a0, b0, c, 0, 0, 0);
        c = __builtin_amdgcn_mfma_f32_16x16x32_bf16(a1, b1, c, 0, 0, 0);
        acc[t] = c;
    }
    const int rb = (lane >> 4) * 4;
    float iq[4];
#pragma unroll
    for (int j = 0; j < 4; ++j) iq[j] = __shfl(invq, rb + j);
#pragma unroll
    for (int j = 0; j < 4; ++j) {
        float m = -1e30f;
#pragma unroll
        for (int t = 0; t < 7; ++t) { acc[t][j] *= iq[j] * RADIUS_F; m = fmaxf(m, acc[t][j]); }
#pragma unroll
        for (int o = 1; o < 16; o <<= 1) m = fmaxf(m, __shfl_xor(m, o));
        float s = 0.f;
#pragma unroll
        for (int t = 0; t < 7; ++t) { float e = __expf(acc[t][j] - m); acc[t][j] = e; s += e; }
#pragma unroll
        for (int o = 1; o < 16; o <<= 1) s += __shfl_xor(s, o);
        const float rs = 1.f / s;
#pragma unroll
        for (int t = 0; t < 7; ++t) acc[t][j] *= rs;
    }
#pragma unroll
    for (int t = 0; t < 7; ++t)
#pragma unroll
        for (int j = 0; j < 4; ++j)
            addr[(size_t)(row0 + rb + j) * 896 + h * 112 + t * 16 + lr] = (__bf16)acc[t][j];
}

// ---------------- recon softmax: one wave per row over 112 slots ----------------
__global__ __launch_bounds__(256) void recon_softmax(const bf16_t* __restrict__ vp,
                                                     const float* __restrict__ sim,
                                                     const float* __restrict__ invmv,
                                                     bf16_t* __restrict__ addr2) {
    const int wid = threadIdx.x >> 6, lane = threadIdx.x & 63;
    const size_t row = (size_t)blockIdx.x * 4 + wid;
    bf16x8 v = *reinterpret_cast<const bf16x8*>(vp + row * 512 + lane * 8);
    float ssq = 0.f;
#pragma unroll
    for (int j = 0; j < 8; ++j) { float x = (float)v[j]; ssq += x * x; }
    ssq = wave_sum(ssq);
    const float invq = 1.f / fmaxf(sqrtf(ssq), 1e-12f);
    float x0 = sim[row * 128 + lane] * invq * invmv[lane] * RADIUS_F;
    float x1 = (lane < 48) ? sim[row * 128 + 64 + lane] * invq * invmv[64 + lane] * RADIUS_F
                           : -1e30f;
    float m = fmaxf(x0, x1);
#pragma unroll
    for (int o = 1; o < 64; o <<= 1) m = fmaxf(m, __shfl_xor(m, o));
    float e0 = __expf(x0 - m);
    float e1 = (lane < 48) ? __expf(x1 - m) : 0.f;
    float s = wave_sum(e0 + e1);
    const float rs = 1.f / s;
    addr2[row * 128 + lane] = (__bf16)(e0 * rs);
    addr2[row * 128 + 64 + lane] = (__bf16)(lane < 48 ? e1 * rs : 0.f);
}

// ---------------- fused GEMM + LN1 (predict): out = LN1(query + A@W^T + ob) ----------------
// tile: 64 rows x 512 cols; grid.x = M/64; 4 waves, wave w -> cols [w*128, w*128+128)
__global__ __launch_bounds__(256) void gemm_ln_predict(
    const bf16_t* __restrict__ A,   // addr [M][896]
    const bf16_t* __restrict__ W,   // wct [512][896]
    const float* __restrict__ ob,
    const float* __restrict__ query,
    const float* __restrict__ g, const float* __restrict__ b,
    float* __restrict__ outp) {
    __shared__ __align__(16) bf16_t As[64 * 32];
    __shared__ __align__(16) bf16_t Bs[512 * 32];
    __shared__ float2 rsum2[64][4];
    const int tid = threadIdx.x;
    const int wid = tid >> 6, lane = tid & 63;
    const int lr = lane & 15, hi = lane >> 4;
    const int ko = hi * 8;
    const size_t rowBase = (size_t)blockIdx.x * 64;
    const int r0 = tid >> 2, c0 = (tid & 3) * 8;
    const bf16_t* a_src = A + (rowBase + r0) * 896 + c0;
    const bf16_t* w_src = W + (size_t)r0 * 896 + c0;
    f32x4 acc[4][8];
#pragma unroll
    for (int m = 0; m < 4; ++m)
#pragma unroll
        for (int n = 0; n < 8; ++n) {
            acc[m][n][0] = 0.f; acc[m][n][1] = 0.f;
            acc[m][n][2] = 0.f; acc[m][n][3] = 0.f;
        }
    for (int k0 = 0; k0 < 896; k0 += 32) {
        __syncthreads();
        gload_lds16(a_src + k0, As + tid * 8);
#pragma unroll
        for (int i = 0; i < 8; ++i)
            gload_lds16(w_src + (size_t)i * 64 * 896 + k0, Bs + i * 2048 + tid * 8);
        __syncthreads();
        bf16x8 af[4], bfr[8];
#pragma unroll
        for (int m = 0; m < 4; ++m)
            af[m] = *reinterpret_cast<const bf16x8*>(As + (m * 16 + lr) * 32 + ko);
#pragma unroll
        for (int n = 0; n < 8; ++n)
            bfr[n] = *reinterpret_cast<const bf16x8*>(Bs + (wid * 128 + n * 16 + lr) * 32 + ko);
#pragma unroll
        for (int m = 0; m < 4; ++m)
#pragma unroll
            for (int n = 0; n < 8; ++n)
                acc[m][n] = __builtin_amdgcn_mfma_f32_16x16x32_bf16(af[m], bfr[n], acc[m][n], 0, 0, 0);
    }
    const int rb = hi * 4;
    float s1[4][4], s2[4][4];
#pragma unroll
    for (int m = 0; m < 4; ++m)
#pragma unroll
        for (int j = 0; j < 4; ++j) { s1[m][j] = 0.f; s2[m][j] = 0.f; }
#pragma unroll
    for (int n = 0; n < 8; ++n) {
        const int col = wid * 128 + n * 16 + lr;
        const float obv = ob[col];
#pragma unroll
        for (int m = 0; m < 4; ++m)
#pragma unroll
            for (int j = 0; j < 4; ++j) {
                const size_t row = rowBase + m * 16 + rb + j;
                float x = acc[m][n][j] + obv + query[row * 512 + col];
                acc[m][n][j] = x;
                s1[m][j] += x;
                s2[m][j] += x * x;
            }
    }
#pragma unroll
    for (int m = 0; m < 4; ++m)
#pragma unroll
        for (int j = 0; j < 4; ++j)
#pragma unroll
            for (int o = 1; o < 16; o <<= 1) {
                s1[m][j] += __shfl_xor(s1[m][j], o);
                s2[m][j] += __shfl_xor(s2[m][j], o);
            }
    if (lr == 0) {
#pragma unroll
        for (int m = 0; m < 4; ++m)
#pragma unroll
            for (int j = 0; j < 4; ++j)
                rsum2[m * 16 + rb + j][wid] = make_float2(s1[m][j], s2[m][j]);
    }
    __syncthreads();
    float mean[4][4], rstd[4][4];
#pragma unroll
    for (int m = 0; m < 4; ++m)
#pragma unroll
        for (int j = 0; j < 4; ++j) {
            const int rl = m * 16 + rb + j;
            float ts = 0.f, ts2 = 0.f;
#pragma unroll
            for (int w = 0; w < 4; ++w) { ts += rsum2[rl][w].x; ts2 += rsum2[rl][w].y; }
            const float mu = ts * (1.f / 512.f);
            mean[m][j] = mu;
            rstd[m][j] = rsqrtf(ts2 * (1.f / 512.f) - mu * mu + LN_EPS);
        }
#pragma unroll
    for (int n = 0; n < 8; ++n) {
        const int col = wid * 128 + n * 16 + lr;
        const float gv = g[col], bv = b[col];
#pragma unroll
        for (int m = 0; m < 4; ++m)
#pragma unroll
            for (int j = 0; j < 4; ++j) {
                const size_t row = rowBase + m * 16 + rb + j;
                outp[row * 512 + col] = (acc[m][n][j] - mean[m][j]) * rstd[m][j] * gv + bv;
            }
    }
}

// ---------------- fused GEMM + cos-loss + LN3 + LN1 (recon) ----------------
// a = A@W^T (K=128); rr += |1-cos(a,value)|; out = LN1(query + LN3(a))
__global__ __launch_bounds__(256) void gemm_ln_recon(
    const bf16_t* __restrict__ A,   // addr2 [M][128]
    const bf16_t* __restrict__ W,   // mvT [512][128]
    const float* __restrict__ query, const float* __restrict__ value,
    const float* __restrict__ g3, const float* __restrict__ b3,
    const float* __restrict__ g1, const float* __restrict__ b1,
    float* __restrict__ outp, float* __restrict__ loss0) {
    __shared__ __align__(16) bf16_t As[64 * 32];
    __shared__ __align__(16) bf16_t Bs[512 * 32];
    __shared__ float4 rsum4[64][4];
    __shared__ float2 rsum2[64][4];
    const int tid = threadIdx.x;
    const int wid = tid >> 6, lane = tid & 63;
    const int lr = lane & 15, hi = lane >> 4;
    const int ko = hi * 8;
    const size_t rowBase = (size_t)blockIdx.x * 64;
    const int r0 = tid >> 2, c0 = (tid & 3) * 8;
    const bf16_t* a_src = A + (rowBase + r0) * 128 + c0;
    const bf16_t* w_src = W + (size_t)r0 * 128 + c0;
    f32x4 acc[4][8];
#pragma unroll
    for (int m = 0; m < 4; ++m)
#pragma unroll
        for (int n = 0; n < 8; ++n) {
            acc[m][n][0] = 0.f; acc[m][n][1] = 0.f;
            acc[m][n][2] = 0.f; acc[m][n][3] = 0.f;
        }
#pragma unroll
    for (int k0 = 0; k0 < 128; k0 += 32) {
        __syncthreads();
        gload_lds16(a_src + k0, As + tid * 8);
#pragma unroll
        for (int i = 0; i < 8; ++i)
            gload_lds16(w_src + (size_t)i * 64 * 128 + k0, Bs + i * 2048 + tid * 8);
        __syncthreads();
        bf16x8 af[4], bfr[8];
#pragma unroll
        for (int m = 0; m < 4; ++m)
            af[m] = *reinterpret_cast<const bf16x8*>(As + (m * 16 + lr) * 32 + ko);
#pragma unroll
        for (int n = 0; n < 8; ++n)
            bfr[n] = *reinterpret_cast<const bf16x8*>(Bs + (wid * 128 + n * 16 + lr) * 32 + ko);
#pragma unroll
        for (int m = 0; m < 4; ++m)
#pragma unroll
            for (int n = 0; n < 8; ++n)
                acc[m][n] = __builtin_amdgcn_mfma_f32_16x16x32_bf16(af[m], bfr[n], acc[m][n], 0, 0, 0);
    }
    const int rb = hi * 4;
    // round 1: stats of a and value
    float sa[4][4], sa2[4][4], sav[4][4], sv2[4][4];
#pragma unroll
    for (int m = 0; m < 4; ++m)
#pragma unroll
        for (int j = 0; j < 4; ++j) { sa[m][j] = 0.f; sa2[m][j] = 0.f; sav[m][j] = 0.f; sv2[m][j] = 0.f; }
#pragma unroll
    for (int n = 0; n < 8; ++n) {
        const int col = wid * 128 + n * 16 + lr;
#pragma unroll
        for (int m = 0; m < 4; ++m)
#pragma unroll
            for (int j = 0; j < 4; ++j) {
                const size_t row = rowBase + m * 16 + rb + j;
                const float a = acc[m][n][j];
                const float v = value[row * 512 + col];
                sa[m][j] += a; sa2[m][j] += a * a;
                sav[m][j] += a * v; sv2[m][j] += v * v;
            }
    }
#pragma unroll
    for (int m = 0; m < 4; ++m)
#pragma unroll
        for (int j = 0; j < 4; ++j)
#pragma unroll
            for (int o = 1; o < 16; o <<= 1) {
                sa[m][j] += __shfl_xor(sa[m][j], o);
                sa2[m][j] += __shfl_xor(sa2[m][j], o);
                sav[m][j] += __shfl_xor(sav[m][j], o);
                sv2[m][j] += __shfl_xor(sv2[m][j], o);
            }
    if (lr == 0) {
#pragma unroll
        for (int m = 0; m < 4; ++m)
#pragma unroll
            for (int j = 0; j < 4; ++j)
                rsum4[m * 16 + rb + j][wid] = make_float4(sa[m][j], sa2[m][j], sav[m][j], sv2[m][j]);
    }
    __syncthreads();
    float m3[4][4], r3[4][4];
    float rrloc = 0.f;
#pragma unroll
    for (int m = 0; m < 4; ++m)
#pragma unroll
        for (int j = 0; j < 4; ++j) {
            const int rl = m * 16 + rb + j;
            float tsa = 0.f, tsa2 = 0.f, tsav = 0.f, tsv2 = 0.f;
#pragma unroll
            for (int w = 0; w < 4; ++w) {
                float4 t = rsum4[rl][w];
                tsa += t.x; tsa2 += t.y; tsav += t.z; tsv2 += t.w;
            }
            const float na = fmaxf(sqrtf(tsa2), 1e-12f);
            const float nv = fmaxf(sqrtf(tsv2), 1e-12f);
            rrloc += fabsf(1.f - tsav / (na * nv));
            const float mu = tsa * (1.f / 512.f);
            m3[m][j] = mu;
            r3[m][j] = rsqrtf(tsa2 * (1.f / 512.f) - mu * mu + LN_EPS);
        }
    if (wid == 0) {
        // every lane of wave 0 computed the same 16 row-stats per hi-group; each row
        // counted 16x across lr -> divide by 16 after the wave reduction.
        rrloc = wave_sum(rrloc);
        if (lane == 0) atomicAdd(loss0, rrloc * (1.f / (16.f * 32768.f)));
    }
    // round 2: x = query + LN3(a)
    float s1[4][4], s2[4][4];
#pragma unroll
    for (int m = 0; m < 4; ++m)
#pragma unroll
        for (int j = 0; j < 4; ++j) { s1[m][j] = 0.f; s2[m][j] = 0.f; }
#pragma unroll
    for (int n = 0; n < 8; ++n) {
        const int col = wid * 128 + n * 16 + lr;
        const float g3v = g3[col], b3v = b3[col];
#pragma unroll
        for (int m = 0; m < 4; ++m)
#pragma unroll
            for (int j = 0; j < 4; ++j) {
                const size_t row = rowBase + m * 16 + rb + j;
                float x = query[row * 512 + col] +
                          (acc[m][n][j] - m3[m][j]) * r3[m][j] * g3v + b3v;
                acc[m][n][j] = x;
                s1[m][j] += x;
                s2[m][j] += x * x;
            }
    }
#pragma unroll
    for (int m = 0; m < 4; ++m)
#pragma unroll
        for (int j = 0; j < 4; ++j)
#pragma unroll
            for (int o = 1; o < 16; o <<= 1) {
                s1[m][j] += __shfl_xor(s1[m][j], o);
                s2[m][j] += __shfl_xor(s2[m][j], o);
            }
    if (lr == 0) {
#pragma unroll
        for (int m = 0; m < 4; ++m)
#pragma unroll
            for (int j = 0; j < 4; ++j)
                rsum2[m * 16 + rb + j][wid] = make_float2(s1[m][j], s2[m][j]);
    }
    __syncthreads();
#pragma unroll
    for (int m = 0; m < 4; ++m)
#pragma unroll
        for (int j = 0; j < 4; ++j) {
            const int rl = m * 16 + rb + j;
            float ts = 0.f, ts2 = 0.f;
#pragma unroll
            for (int w = 0; w < 4; ++w) { ts += rsum2[rl][w].x; ts2 += rsum2[rl][w].y; }
            const float mu = ts * (1.f / 512.f);
            m3[m][j] = mu;
            r3[m][j] = rsqrtf(ts2 * (1.f / 512.f) - mu * mu + LN_EPS);
        }
#pragma unroll
    for (int n = 0; n < 8; ++n) {
        const int col = wid * 128 + n * 16 + lr;
        const float gv = g1[col], bv = b1[col];
#pragma unroll
        for (int m = 0; m < 4; ++m)
#pragma unroll
            for (int j = 0; j < 4; ++j) {
                const size_t row = rowBase + m * 16 + rb + j;
                outp[row * 512 + col] = (acc[m][n][j] - m3[m][j]) * r3[m][j] * gv + bv;
            }
    }
}

extern "C" void kernel_launch(void* const* d_in, const int* in_sizes, int n_in,
                              void* d_out, int out_size, void* d_ws, size_t ws_size,
                              hipStream_t stream) {
    const float* query = (const float*)d_in[0];
    const float* value = (const float*)d_in[1];
    const float* mem_key = (const float*)d_in[2];
    const float* mem_value = (const float*)d_in[3];
    const float* q_w = (const float*)d_in[4];
    const float* q_b = (const float*)d_in[5];
    const float* v_w = (const float*)d_in[6];
    const float* v_b = (const float*)d_in[7];
    const float* out_w = (const float*)d_in[8];
    const float* out_b = (const float*)d_in[9];
    const float* ln1_g = (const float*)d_in[10];
    const float* ln1_b = (const float*)d_in[11];
    const float* ln3_g = (const float*)d_in[12];
    const float* ln3_b = (const float*)d_in[13];
    float* out = (float*)d_out;

    char* ws = (char*)d_ws;
    size_t off = 0;
    auto alloc = [&](size_t bytes) {
        void* p = ws + off;
        off += (bytes + 255) & ~(size_t)255;
        return p;
    };
    bf16_t* bufB = (bf16_t*)alloc(16777216ull * 2);    // qp_bf16, then v_proj_bf16
    bf16_t* addr = (bf16_t*)alloc(32768ull * 896 * 2); // addr, later addr2
    float* sim = (float*)alloc(32768ull * 128 * 4);
    bf16_t* qwb = (bf16_t*)alloc(262144ull * 2);
    bf16_t* vwb = (bf16_t*)alloc(262144ull * 2);
    bf16_t* owb = (bf16_t*)alloc(2097152ull * 2);
    bf16_t* wct = (bf16_t*)alloc(896ull * 512 * 2);    // WcT[512][896]
    bf16_t* keyn = (bf16_t*)alloc(896ull * 64 * 2);
    bf16_t* mvb = (bf16_t*)alloc(128ull * 512 * 2);    // padded to 128 rows
    bf16_t* mvT = (bf16_t*)alloc(512ull * 128 * 2);
    float* invmv = (float*)alloc(112 * 4);
    bf16_t* addr2 = addr;

    float* f_predict = out;
    float* f_recon = out + 16777216;
    float* loss_slots = out + 33554432;  // [recon_loss, contrastive_loss]

    // prep
    cast_k<<<256, 256, 0, stream>>>(q_w, qwb, 65536);
    cast_k<<<256, 256, 0, stream>>>(v_w, vwb, 65536);
    cast_k<<<2048, 256, 0, stream>>>(out_w, owb, 524288);
    keyn_k<<<224, 256, 0, stream>>>(mem_key, keyn);
    mv_prep_k<<<128, 256, 0, stream>>>(mem_value, mvb, invmv, loss_slots);
    mvT_k<<<256, 256, 0, stream>>>(mem_value, mvT);
    contrastive_k<<<112, 256, 0, stream>>>(mem_value, invmv, loss_slots + 1);
    // WcT[d][h*112+s] = sum_j out_w[d][h*512+j] * mem_value[s][j]
    gemm_bt<<<dim3(8, 2, 8), 256, 0, stream>>>(owb, 4096, 512, mvb, 512, 0,
                                               wct, 896, 112, 512, 112, 512);
    // predict branch
    gemm128_f32a<<<dim3(256, 4), 256, 0, stream>>>(query, 512, qwb, 512, q_b,
                                                   bufB, 512, 512);
    addr_predict<<<dim3(512, 8), 256, 0, stream>>>(bufB, keyn, addr);
    gemm_ln_predict<<<512, 256, 0, stream>>>(addr, wct, out_b, query,
                                             ln1_g, ln1_b, f_predict);
    // recon branch
    gemm128_f32a<<<dim3(256, 4), 256, 0, stream>>>(value, 512, vwb, 512, v_b,
                                                   bufB, 512, 512);
    gemm128<<<dim3(256, 1), 256, 0, stream>>>(bufB, 512, mvb, 512, sim, 128, 512);
    recon_softmax<<<8192, 256, 0, stream>>>(bufB, sim, invmv, addr2);
    gemm_ln_recon<<<512, 256, 0, stream>>>(addr2, mvT, query, value,
                                           ln3_g, ln3_b, ln1_g, ln1_b,
                                           f_recon, loss_slots);
}

// Round 4
// 360.218 us; speedup vs baseline: 2.4982x; 1.0311x over previous
//
#include <hip/hip_runtime.h>
#include <hip/hip_bf16.h>
#include <math.h>

typedef __bf16 bf16_t;
typedef __attribute__((ext_vector_type(8))) __bf16 bf16x8;
typedef __attribute__((ext_vector_type(4))) __bf16 bf16x4;
typedef __attribute__((ext_vector_type(4))) float f32x4;

#define LN_EPS 1e-5f
#define RADIUS_F 16.0f

__device__ inline bf16x8 zero8() {
    bf16x8 v;
#pragma unroll
    for (int i = 0; i < 8; ++i) v[i] = (__bf16)0.f;
    return v;
}

__device__ inline float wave_sum(float v) {
#pragma unroll
    for (int o = 1; o < 64; o <<= 1) v += __shfl_xor(v, o);
    return v;
}

__device__ inline void gload_lds16(const bf16_t* g, bf16_t* l) {
    __builtin_amdgcn_global_load_lds(
        (const __attribute__((address_space(1))) void*)g,
        (__attribute__((address_space(3))) void*)l, 16, 0, 0);
}

__device__ inline void drain_barrier() {
    asm volatile("s_waitcnt vmcnt(0)" ::: "memory");
    __builtin_amdgcn_s_barrier();
}

// ---------------- casts (weights only) ----------------
__global__ __launch_bounds__(256) void cast_k(const float* __restrict__ in,
                                              bf16_t* __restrict__ out, int n4) {
    int i = blockIdx.x * 256 + threadIdx.x;
    if (i < n4) {
        float4 v = reinterpret_cast<const float4*>(in)[i];
        bf16x4 o;
        o[0] = (__bf16)v.x; o[1] = (__bf16)v.y; o[2] = (__bf16)v.z; o[3] = (__bf16)v.w;
        reinterpret_cast<bf16x4*>(out)[i] = o;
    }
}

// normalize mem_key rows (896 x 64) -> bf16
__global__ __launch_bounds__(256) void keyn_k(const float* __restrict__ mk,
                                              bf16_t* __restrict__ kn) {
    int row = blockIdx.x * 4 + (threadIdx.x >> 6);
    int lane = threadIdx.x & 63;
    float x = mk[(size_t)row * 64 + lane];
    float ss = wave_sum(x * x);
    kn[(size_t)row * 64 + lane] = (__bf16)(x / fmaxf(sqrtf(ss), 1e-12f));
}

// mem_value: row inv-norms + bf16 copy (padded to 128 rows); zero loss slots
__global__ __launch_bounds__(256) void mv_prep_k(const float* __restrict__ mv,
                                                 bf16_t* __restrict__ mvb,
                                                 float* __restrict__ invmv,
                                                 float* __restrict__ loss_slots) {
    const int s = blockIdx.x, tid = threadIdx.x;
    if (s >= 112) {
        mvb[(size_t)s * 512 + tid * 2] = (__bf16)0.f;
        mvb[(size_t)s * 512 + tid * 2 + 1] = (__bf16)0.f;
        return;
    }
    float2 x = *reinterpret_cast<const float2*>(mv + (size_t)s * 512 + tid * 2);
    float ss = wave_sum(x.x * x.x + x.y * x.y);
    __shared__ float red[4];
    int wid = tid >> 6, lane = tid & 63;
    if (lane == 0) red[wid] = ss;
    __syncthreads();
    ss = red[0] + red[1] + red[2] + red[3];
    if (tid == 0) invmv[s] = 1.f / fmaxf(sqrtf(ss), 1e-12f);
    mvb[(size_t)s * 512 + tid * 2] = (__bf16)x.x;
    mvb[(size_t)s * 512 + tid * 2 + 1] = (__bf16)x.y;
    if (s == 0 && tid < 2) loss_slots[tid] = 0.f;
}

// mem_value transposed + zero-padded to [512][128] bf16
__global__ __launch_bounds__(256) void mvT_k(const float* __restrict__ mv,
                                             bf16_t* __restrict__ mvT) {
    int idx = blockIdx.x * 256 + threadIdx.x;  // 512*128
    int j = idx >> 7, s = idx & 127;
    mvT[idx] = (__bf16)(s < 112 ? mv[(size_t)s * 512 + j] : 0.f);
}

// contrastive loss: sum |I - Gn Gn^T| * 0.01  (fp32)
__global__ __launch_bounds__(256) void contrastive_k(const float* __restrict__ mv,
                                                     const float* __restrict__ invmv,
                                                     float* __restrict__ out_slot) {
    const int a = blockIdx.x;
    const int tid = threadIdx.x, wid = tid >> 6, lane = tid & 63;
    __shared__ float rowa[512];
    __shared__ float wsum[4];
    for (int i = tid; i < 512; i += 256) rowa[i] = mv[(size_t)a * 512 + i];
    __syncthreads();
    float acc = 0.f;
    const float ia = invmv[a];
    for (int b = wid; b < 112; b += 4) {
        float d = 0.f;
#pragma unroll
        for (int i = 0; i < 8; ++i) d += rowa[lane + i * 64] * mv[(size_t)b * 512 + lane + i * 64];
        d = wave_sum(d);
        float gv = d * ia * invmv[b];
        acc += fabsf((a == b ? 1.f : 0.f) - gv);
    }
    if (lane == 0) wsum[wid] = acc;
    __syncthreads();
    if (tid == 0) atomicAdd(out_slot, (wsum[0] + wsum[1] + wsum[2] + wsum[3]) * 0.01f);
}

// ---------------- 128x128 LDS-staged GEMM, A = fp32 (reg-staged + cvt) ----------------
__global__ __launch_bounds__(256) void gemm128_f32a(
    const float* __restrict__ A, int lda,
    const bf16_t* __restrict__ W, int ldw,
    const float* __restrict__ bias,
    bf16_t* __restrict__ Cb, int ldc, int K) {
    __shared__ __align__(16) bf16_t As[128 * 32];
    __shared__ __align__(16) bf16_t Bs[128 * 32];
    const int tid = threadIdx.x;
    const int wid = tid >> 6, lane = tid & 63;
    const int wr = wid >> 1, wc = wid & 1;
    const int lr = lane & 15;
    const int ko = (lane >> 4) * 8;
    const size_t rowBase = (size_t)blockIdx.x * 128;
    const size_t colBase = (size_t)blockIdx.y * 128;
    const int r0 = tid >> 2;
    const int c0 = (tid & 3) * 8;
    const float* a_src = A + (rowBase + r0) * lda + c0;
    const bf16_t* w_src = W + (colBase + r0) * ldw + c0;
    f32x4 acc[4][4];
#pragma unroll
    for (int m = 0; m < 4; ++m)
#pragma unroll
        for (int n = 0; n < 4; ++n) {
            acc[m][n][0] = 0.f; acc[m][n][1] = 0.f;
            acc[m][n][2] = 0.f; acc[m][n][3] = 0.f;
        }
    for (int k0 = 0; k0 < K; k0 += 32) {
        float4 a0 = *reinterpret_cast<const float4*>(a_src + k0);
        float4 a1 = *reinterpret_cast<const float4*>(a_src + k0 + 4);
        float4 a2 = *reinterpret_cast<const float4*>(a_src + (size_t)64 * lda + k0);
        float4 a3 = *reinterpret_cast<const float4*>(a_src + (size_t)64 * lda + k0 + 4);
        __syncthreads();
        gload_lds16(w_src + k0, Bs + tid * 8);
        gload_lds16(w_src + (size_t)64 * ldw + k0, Bs + 2048 + tid * 8);
        bf16x8 p0, p1;
        p0[0] = (__bf16)a0.x; p0[1] = (__bf16)a0.y; p0[2] = (__bf16)a0.z; p0[3] = (__bf16)a0.w;
        p0[4] = (__bf16)a1.x; p0[5] = (__bf16)a1.y; p0[6] = (__bf16)a1.z; p0[7] = (__bf16)a1.w;
        p1[0] = (__bf16)a2.x; p1[1] = (__bf16)a2.y; p1[2] = (__bf16)a2.z; p1[3] = (__bf16)a2.w;
        p1[4] = (__bf16)a3.x; p1[5] = (__bf16)a3.y; p1[6] = (__bf16)a3.z; p1[7] = (__bf16)a3.w;
        *reinterpret_cast<bf16x8*>(As + tid * 8) = p0;
        *reinterpret_cast<bf16x8*>(As + 2048 + tid * 8) = p1;
        __syncthreads();
        bf16x8 af[4], bfr[4];
#pragma unroll
        for (int m = 0; m < 4; ++m)
            af[m] = *reinterpret_cast<const bf16x8*>(As + (wr * 64 + m * 16 + lr) * 32 + ko);
#pragma unroll
        for (int n = 0; n < 4; ++n)
            bfr[n] = *reinterpret_cast<const bf16x8*>(Bs + (wc * 64 + n * 16 + lr) * 32 + ko);
#pragma unroll
        for (int m = 0; m < 4; ++m)
#pragma unroll
            for (int n = 0; n < 4; ++n)
                acc[m][n] = __builtin_amdgcn_mfma_f32_16x16x32_bf16(af[m], bfr[n], acc[m][n], 0, 0, 0);
    }
    const int rj = (lane >> 4) * 4;
#pragma unroll
    for (int n = 0; n < 4; ++n) {
        const int col = (int)colBase + wc * 64 + n * 16 + lr;
        const float bv = bias ? bias[col] : 0.f;
#pragma unroll
        for (int m = 0; m < 4; ++m) {
            const size_t r = rowBase + wr * 64 + m * 16 + rj;
#pragma unroll
            for (int j = 0; j < 4; ++j)
                Cb[(r + j) * ldc + col] = (__bf16)(acc[m][n][j] + bv);
        }
    }
}

// ---------------- small direct GEMM (WcT fold only) ----------------
__global__ __launch_bounds__(256) void gemm_bt(
    const bf16_t* __restrict__ A, int lda, int aZ,
    const bf16_t* __restrict__ W, int ldw, int wZ,
    bf16_t* __restrict__ Cb, int ldc, int cZ,
    int M, int N, int K) {
    const int wid = threadIdx.x >> 6;
    const int lane = threadIdx.x & 63;
    const int lr = lane & 15;
    const int kk = (lane >> 4) * 8;
    const int row0 = blockIdx.x * 64 + wid * 16;
    const int col0 = blockIdx.y * 64;
    A += (size_t)blockIdx.z * aZ;
    W += (size_t)blockIdx.z * wZ;
    const bf16_t* a_ptr = A + (size_t)(row0 + lr) * lda + kk;
    const bf16_t* w_ptr = W + (size_t)(col0 + lr) * ldw + kk;
    f32x4 acc[4];
#pragma unroll
    for (int t = 0; t < 4; ++t) { acc[t][0] = 0.f; acc[t][1] = 0.f; acc[t][2] = 0.f; acc[t][3] = 0.f; }
    bool colv[4];
#pragma unroll
    for (int t = 0; t < 4; ++t) colv[t] = (col0 + t * 16 + lr) < N;
    for (int k0 = 0; k0 < K; k0 += 32) {
        bf16x8 a = *reinterpret_cast<const bf16x8*>(a_ptr + k0);
#pragma unroll
        for (int t = 0; t < 4; ++t) {
            bf16x8 b;
            if (colv[t]) b = *reinterpret_cast<const bf16x8*>(w_ptr + (size_t)t * 16 * ldw + k0);
            else b = zero8();
            acc[t] = __builtin_amdgcn_mfma_f32_16x16x32_bf16(a, b, acc[t], 0, 0, 0);
        }
    }
    const int rb = (lane >> 4) * 4;
    Cb += (size_t)blockIdx.z * cZ;
#pragma unroll
    for (int t = 0; t < 4; ++t) {
        int col = col0 + t * 16 + lr;
        if (col >= N) continue;
#pragma unroll
        for (int j = 0; j < 4; ++j) {
            int r = row0 + rb + j;
            Cb[(size_t)r * ldc + col] = (__bf16)acc[t][j];
        }
    }
}

// ---------------- predict addressing: sim -> softmax -> addr bf16 [N,896] ----------------
__global__ __launch_bounds__(256) void addr_predict(const bf16_t* __restrict__ qp,
                                                    const bf16_t* __restrict__ keyn,
                                                    bf16_t* __restrict__ addr) {
    const int wid = threadIdx.x >> 6, lane = threadIdx.x & 63;
    const int lr = lane & 15, kk = (lane >> 4) * 8;
    const int h = blockIdx.y;
    const int row0 = blockIdx.x * 64 + wid * 16;
    const bf16_t* a_ptr = qp + (size_t)(row0 + lr) * 512 + h * 64 + kk;
    bf16x8 a0 = *reinterpret_cast<const bf16x8*>(a_ptr);
    bf16x8 a1 = *reinterpret_cast<const bf16x8*>(a_ptr + 32);
    float ssq = 0.f;
#pragma unroll
    for (int j = 0; j < 8; ++j) {
        float x = (float)a0[j], y = (float)a1[j];
        ssq += x * x + y * y;
    }
    ssq += __shfl_xor(ssq, 16);
    ssq += __shfl_xor(ssq, 32);
    const float invq = 1.f / fmaxf(sqrtf(ssq), 1e-12f);
    f32x4 acc[7];
#pragma unroll
    for (int t = 0; t < 7; ++t) {
        const bf16_t* b_ptr = keyn + (size_t)(h * 112 + t * 16 + lr) * 64 + kk;
        bf16x8 b0 = *reinterpret_cast<const bf16x8*>(b_ptr);
        bf16x8 b1 = *reinterpret_cast<const bf16x8*>(b_ptr + 32);
        f32x4 c; c[0] = 0.f; c[1] = 0.f; c[2] = 0.f; c[3] = 0.f;
        c = __builtin_amdgcn_mfma_f32_16x16x32_bf16(a0, b0, c, 0, 0, 0);
        c = __builtin_amdgcn_mfma_f32_16x16x32_bf16(a1, b1, c, 0, 0, 0);
        acc[t] = c;
    }
    const int rb = (lane >> 4) * 4;
    float iq[4];
#pragma unroll
    for (int j = 0; j < 4; ++j) iq[j] = __shfl(invq, rb + j);
#pragma unroll
    for (int j = 0; j < 4; ++j) {
        float m = -1e30f;
#pragma unroll
        for (int t = 0; t < 7; ++t) { acc[t][j] *= iq[j] * RADIUS_F; m = fmaxf(m, acc[t][j]); }
#pragma unroll
        for (int o = 1; o < 16; o <<= 1) m = fmaxf(m, __shfl_xor(m, o));
        float s = 0.f;
#pragma unroll
        for (int t = 0; t < 7; ++t) { float e = __expf(acc[t][j] - m); acc[t][j] = e; s += e; }
#pragma unroll
        for (int o = 1; o < 16; o <<= 1) s += __shfl_xor(s, o);
        const float rs = 1.f / s;
#pragma unroll
        for (int t = 0; t < 7; ++t) acc[t][j] *= rs;
    }
#pragma unroll
    for (int t = 0; t < 7; ++t)
#pragma unroll
        for (int j = 0; j < 4; ++j)
            addr[(size_t)(row0 + rb + j) * 896 + h * 112 + t * 16 + lr] = (__bf16)acc[t][j];
}

// ---------------- fused recon sim GEMM + softmax -> addr2 [M][128] ----------------
// 128 rows x 128 cols per block, 4 waves stacked by rows (32 rows each), dbuf.
// ||vp_row|| accumulated in-register from the A fragments during the K-loop.
__global__ __launch_bounds__(256, 2) void gemm_sim_softmax(
    const bf16_t* __restrict__ vp,   // [M][512]
    const bf16_t* __restrict__ mvb,  // [128][512] (rows 112..127 zero)
    const float* __restrict__ invmv, // [112]
    bf16_t* __restrict__ addr2) {    // [M][128]
    __shared__ __align__(16) bf16_t As[2][128 * 32];
    __shared__ __align__(16) bf16_t Bs[2][128 * 32];
    const int tid = threadIdx.x;
    const int wid = tid >> 6, lane = tid & 63;
    const int lr = lane & 15, hi = lane >> 4;
    const int ko = hi * 8;
    const size_t rowBase = (size_t)blockIdx.x * 128;
    const int r0 = tid >> 2, c0 = (tid & 3) * 8;
    const bf16_t* a_src = vp + (rowBase + r0) * 512 + c0;
    const bf16_t* b_src = mvb + (size_t)r0 * 512 + c0;
    f32x4 acc[2][8];
#pragma unroll
    for (int m = 0; m < 2; ++m)
#pragma unroll
        for (int n = 0; n < 8; ++n) {
            acc[m][n][0] = 0.f; acc[m][n][1] = 0.f;
            acc[m][n][2] = 0.f; acc[m][n][3] = 0.f;
        }
    float ssq[2] = {0.f, 0.f};
    auto stage = [&](int buf, int ks) {
        const int k0 = ks * 32;
        gload_lds16(a_src + k0, &As[buf][tid * 8]);
        gload_lds16(a_src + (size_t)64 * 512 + k0, &As[buf][2048 + tid * 8]);
        gload_lds16(b_src + k0, &Bs[buf][tid * 8]);
        gload_lds16(b_src + (size_t)64 * 512 + k0, &Bs[buf][2048 + tid * 8]);
    };
    stage(0, 0);
    drain_barrier();
    int cur = 0;
    for (int ks = 0; ks < 16; ++ks) {
        if (ks < 15) stage(cur ^ 1, ks + 1);
        bf16x8 af[2], bfr[8];
#pragma unroll
        for (int m = 0; m < 2; ++m)
            af[m] = *reinterpret_cast<const bf16x8*>(&As[cur][(wid * 32 + m * 16 + lr) * 32 + ko]);
#pragma unroll
        for (int n = 0; n < 8; ++n)
            bfr[n] = *reinterpret_cast<const bf16x8*>(&Bs[cur][(n * 16 + lr) * 32 + ko]);
#pragma unroll
        for (int m = 0; m < 2; ++m) {
#pragma unroll
            for (int j = 0; j < 8; ++j) { float x = (float)af[m][j]; ssq[m] += x * x; }
#pragma unroll
            for (int n = 0; n < 8; ++n)
                acc[m][n] = __builtin_amdgcn_mfma_f32_16x16x32_bf16(af[m], bfr[n], acc[m][n], 0, 0, 0);
        }
        drain_barrier();
        cur ^= 1;
    }
    // full-row ssq: reduce across the 4 hi-groups (same lr = same row)
#pragma unroll
    for (int m = 0; m < 2; ++m) {
        ssq[m] += __shfl_xor(ssq[m], 16);
        ssq[m] += __shfl_xor(ssq[m], 32);
        ssq[m] = 1.f / fmaxf(sqrtf(ssq[m]), 1e-12f);
    }
    const int rb = hi * 4;
    float imv[7];
#pragma unroll
    for (int n = 0; n < 7; ++n) imv[n] = invmv[n * 16 + lr];
#pragma unroll
    for (int m = 0; m < 2; ++m)
#pragma unroll
        for (int j = 0; j < 4; ++j) {
            const float iq = __shfl(ssq[m], (lane & 48) | (rb + j));
            float x[7];
            float mx = -1e30f;
#pragma unroll
            for (int n = 0; n < 7; ++n) {
                x[n] = acc[m][n][j] * iq * imv[n] * RADIUS_F;
                mx = fmaxf(mx, x[n]);
            }
#pragma unroll
            for (int o = 1; o < 16; o <<= 1) mx = fmaxf(mx, __shfl_xor(mx, o));
            float s = 0.f;
#pragma unroll
            for (int n = 0; n < 7; ++n) { x[n] = __expf(x[n] - mx); s += x[n]; }
#pragma unroll
            for (int o = 1; o < 16; o <<= 1) s += __shfl_xor(s, o);
            const float rs = 1.f / s;
            const size_t row = rowBase + wid * 32 + m * 16 + rb + j;
#pragma unroll
            for (int n = 0; n < 7; ++n)
                addr2[row * 128 + n * 16 + lr] = (__bf16)(x[n] * rs);
            addr2[row * 128 + 112 + lr] = (__bf16)0.f;
        }
}

// ---------------- fused GEMM + LN1 (predict), 128x512 tile, 8 waves, dbuf ----------------
// out = LN1(query + A@W^T + ob); grid.x = M/128
__global__ __launch_bounds__(512, 2) void gemm_ln_predict(
    const bf16_t* __restrict__ A,   // addr [M][896]
    const bf16_t* __restrict__ W,   // wct [512][896]
    const float* __restrict__ ob,
    const float* __restrict__ query,
    const float* __restrict__ g, const float* __restrict__ b,
    float* __restrict__ outp) {
    __shared__ __align__(16) bf16_t As[2][128 * 32];
    __shared__ __align__(16) bf16_t Bs[2][512 * 32];
    __shared__ float2 rsum2[128][4];
    const int tid = threadIdx.x;
    const int wid = tid >> 6, lane = tid & 63;
    const int wr = wid >> 2, wc = wid & 3;
    const int lr = lane & 15, hi = lane >> 4;
    const int ko = hi * 8;
    const size_t rowBase = (size_t)blockIdx.x * 128;
    const int r0 = tid >> 2, c0 = (tid & 3) * 8;
    const bf16_t* a_src = A + (rowBase + r0) * 896 + c0;
    const bf16_t* w_src = W + (size_t)r0 * 896 + c0;
    f32x4 acc[4][8];
#pragma unroll
    for (int m = 0; m < 4; ++m)
#pragma unroll
        for (int n = 0; n < 8; ++n) {
            acc[m][n][0] = 0.f; acc[m][n][1] = 0.f;
            acc[m][n][2] = 0.f; acc[m][n][3] = 0.f;
        }
    auto stage = [&](int buf, int ks) {
        const int k0 = ks * 32;
        gload_lds16(a_src + k0, &As[buf][tid * 8]);
#pragma unroll
        for (int i = 0; i < 4; ++i)
            gload_lds16(w_src + (size_t)i * 128 * 896 + k0, &Bs[buf][i * 4096 + tid * 8]);
    };
    stage(0, 0);
    drain_barrier();
    int cur = 0;
    for (int ks = 0; ks < 28; ++ks) {
        if (ks < 27) stage(cur ^ 1, ks + 1);
        bf16x8 af[4], bfr[8];
#pragma unroll
        for (int m = 0; m < 4; ++m)
            af[m] = *reinterpret_cast<const bf16x8*>(&As[cur][(wr * 64 + m * 16 + lr) * 32 + ko]);
#pragma unroll
        for (int n = 0; n < 8; ++n)
            bfr[n] = *reinterpret_cast<const bf16x8*>(&Bs[cur][(wc * 128 + n * 16 + lr) * 32 + ko]);
#pragma unroll
        for (int m = 0; m < 4; ++m)
#pragma unroll
            for (int n = 0; n < 8; ++n)
                acc[m][n] = __builtin_amdgcn_mfma_f32_16x16x32_bf16(af[m], bfr[n], acc[m][n], 0, 0, 0);
        drain_barrier();
        cur ^= 1;
    }
    const int rb = hi * 4;
    float s1[4][4], s2[4][4];
#pragma unroll
    for (int m = 0; m < 4; ++m)
#pragma unroll
        for (int j = 0; j < 4; ++j) { s1[m][j] = 0.f; s2[m][j] = 0.f; }
#pragma unroll
    for (int n = 0; n < 8; ++n) {
        const int col = wc * 128 + n * 16 + lr;
        const float obv = ob[col];
#pragma unroll
        for (int m = 0; m < 4; ++m)
#pragma unroll
            for (int j = 0; j < 4; ++j) {
                const size_t row = rowBase + wr * 64 + m * 16 + rb + j;
                float x = acc[m][n][j] + obv + query[row * 512 + col];
                acc[m][n][j] = x;
                s1[m][j] += x;
                s2[m][j] += x * x;
            }
    }
#pragma unroll
    for (int m = 0; m < 4; ++m)
#pragma unroll
        for (int j = 0; j < 4; ++j)
#pragma unroll
            for (int o = 1; o < 16; o <<= 1) {
                s1[m][j] += __shfl_xor(s1[m][j], o);
                s2[m][j] += __shfl_xor(s2[m][j], o);
            }
    __syncthreads();
    if (lr == 0) {
#pragma unroll
        for (int m = 0; m < 4; ++m)
#pragma unroll
            for (int j = 0; j < 4; ++j)
                rsum2[wr * 64 + m * 16 + rb + j][wc] = make_float2(s1[m][j], s2[m][j]);
    }
    __syncthreads();
    float mean[4][4], rstd[4][4];
#pragma unroll
    for (int m = 0; m < 4; ++m)
#pragma unroll
        for (int j = 0; j < 4; ++j) {
            const int rl = wr * 64 + m * 16 + rb + j;
            float ts = 0.f, ts2 = 0.f;
#pragma unroll
            for (int w = 0; w < 4; ++w) { ts += rsum2[rl][w].x; ts2 += rsum2[rl][w].y; }
            const float mu = ts * (1.f / 512.f);
            mean[m][j] = mu;
            rstd[m][j] = rsqrtf(ts2 * (1.f / 512.f) - mu * mu + LN_EPS);
        }
#pragma unroll
    for (int n = 0; n < 8; ++n) {
        const int col = wc * 128 + n * 16 + lr;
        const float gv = g[col], bv = b[col];
#pragma unroll
        for (int m = 0; m < 4; ++m)
#pragma unroll
            for (int j = 0; j < 4; ++j) {
                const size_t row = rowBase + wr * 64 + m * 16 + rb + j;
                outp[row * 512 + col] = (acc[m][n][j] - mean[m][j]) * rstd[m][j] * gv + bv;
            }
    }
}

// ---------------- fused GEMM + cos-loss + LN3 + LN1 (recon), 128x512, dbuf ----------------
__global__ __launch_bounds__(512, 2) void gemm_ln_recon(
    const bf16_t* __restrict__ A,   // addr2 [M][128]
    const bf16_t* __restrict__ W,   // mvT [512][128]
    const float* __restrict__ query, const float* __restrict__ value,
    const float* __restrict__ g3, const float* __restrict__ b3,
    const float* __restrict__ g1, const float* __restrict__ b1,
    float* __restrict__ outp, float* __restrict__ loss0) {
    __shared__ __align__(16) bf16_t As[2][128 * 32];
    __shared__ __align__(16) bf16_t Bs[2][512 * 32];
    __shared__ float4 rsum4[128][4];
    __shared__ float2 rsum2[128][4];
    const int tid = threadIdx.x;
    const int wid = tid >> 6, lane = tid & 63;
    const int wr = wid >> 2, wc = wid & 3;
    const int lr = lane & 15, hi = lane >> 4;
    const int ko = hi * 8;
    const size_t rowBase = (size_t)blockIdx.x * 128;
    const int r0 = tid >> 2, c0 = (tid & 3) * 8;
    const bf16_t* a_src = A + (rowBase + r0) * 128 + c0;
    const bf16_t* w_src = W + (size_t)r0 * 128 + c0;
    f32x4 acc[4][8];
#pragma unroll
    for (int m = 0; m < 4; ++m)
#pragma unroll
        for (int n = 0; n < 8; ++n) {
            acc[m][n][0] = 0.f; acc[m][n][1] = 0.f;
            acc[m][n][2] = 0.f; acc[m][n][3] = 0.f;
        }
    auto stage = [&](int buf, int ks) {
        const int k0 = ks * 32;
        gload_lds16(a_src + k0, &As[buf][tid * 8]);
#pragma unroll
        for (int i = 0; i < 4; ++i)
            gload_lds16(w_src + (size_t)i * 128 * 128 + k0, &Bs[buf][i * 4096 + tid * 8]);
    };
    stage(0, 0);
    drain_barrier();
    int cur = 0;
#pragma unroll
    for (int ks = 0; ks < 4; ++ks) {
        if (ks < 3) stage(cur ^ 1, ks + 1);
        bf16x8 af[4], bfr[8];
#pragma unroll
        for (int m = 0; m < 4; ++m)
            af[m] = *reinterpret_cast<const bf16x8*>(&As[cur][(wr * 64 + m * 16 + lr) * 32 + ko]);
#pragma unroll
        for (int n = 0; n < 8; ++n)
            bfr[n] = *reinterpret_cast<const bf16x8*>(&Bs[cur][(wc * 128 + n * 16 + lr) * 32 + ko]);
#pragma unroll
        for (int m = 0; m < 4; ++m)
#pragma unroll
            for (int n = 0; n < 8; ++n)
                acc[m][n] = __builtin_amdgcn_mfma_f32_16x16x32_bf16(af[m], bfr[n], acc[m][n], 0, 0, 0);
        drain_barrier();
        cur ^= 1;
    }
    const int rb = hi * 4;
    // round 1: stats of a and value
    float sa[4][4], sa2[4][4], sav[4][4], sv2[4][4];
#pragma unroll
    for (int m = 0; m < 4; ++m)
#pragma unroll
        for (int j = 0; j < 4; ++j) { sa[m][j] = 0.f; sa2[m][j] = 0.f; sav[m][j] = 0.f; sv2[m][j] = 0.f; }
#pragma unroll
    for (int n = 0; n < 8; ++n) {
        const int col = wc * 128 + n * 16 + lr;
#pragma unroll
        for (int m = 0; m < 4; ++m)
#pragma unroll
            for (int j = 0; j < 4; ++j) {
                const size_t row = rowBase + wr * 64 + m * 16 + rb + j;
                const float a = acc[m][n][j];
                const float v = value[row * 512 + col];
                sa[m][j] += a; sa2[m][j] += a * a;
                sav[m][j] += a * v; sv2[m][j] += v * v;
            }
    }
#pragma unroll
    for (int m = 0; m < 4; ++m)
#pragma unroll
        for (int j = 0; j < 4; ++j)
#pragma unroll
            for (int o = 1; o < 16; o <<= 1) {
                sa[m][j] += __shfl_xor(sa[m][j], o);
                sa2[m][j] += __shfl_xor(sa2[m][j], o);
                sav[m][j] += __shfl_xor(sav[m][j], o);
                sv2[m][j] += __shfl_xor(sv2[m][j], o);
            }
    __syncthreads();
    if (lr == 0) {
#pragma unroll
        for (int m = 0; m < 4; ++m)
#pragma unroll
            for (int j = 0; j < 4; ++j)
                rsum4[wr * 64 + m * 16 + rb + j][wc] = make_float4(sa[m][j], sa2[m][j], sav[m][j], sv2[m][j]);
    }
    __syncthreads();
    float m3[4][4], r3[4][4];
    float rrloc = 0.f;
#pragma unroll
    for (int m = 0; m < 4; ++m)
#pragma unroll
        for (int j = 0; j < 4; ++j) {
            const int rl = wr * 64 + m * 16 + rb + j;
            float tsa = 0.f, tsa2 = 0.f, tsav = 0.f, tsv2 = 0.f;
#pragma unroll
            for (int w = 0; w < 4; ++w) {
                float4 t = rsum4[rl][w];
                tsa += t.x; tsa2 += t.y; tsav += t.z; tsv2 += t.w;
            }
            const float na = fmaxf(sqrtf(tsa2), 1e-12f);
            const float nv = fmaxf(sqrtf(tsv2), 1e-12f);
            rrloc += fabsf(1.f - tsav / (na * nv));
            const float mu = tsa * (1.f / 512.f);
            m3[m][j] = mu;
            r3[m][j] = rsqrtf(tsa2 * (1.f / 512.f) - mu * mu + LN_EPS);
        }
    if (wc == 0) {
        // each row's rrloc is replicated across the 16 lr lanes -> /16
        rrloc = wave_sum(rrloc);
        if (lane == 0) atomicAdd(loss0, rrloc * (1.f / (16.f * 32768.f)));
    }
    // round 2: x = query + LN3(a)
    float s1[4][4], s2[4][4];
#pragma unroll
    for (int m = 0; m < 4; ++m)
#pragma unroll
        for (int j = 0; j < 4; ++j) { s1[m][j] = 0.f; s2[m][j] = 0.f; }
#pragma unroll
    for (int n = 0; n < 8; ++n) {
        const int col = wc * 128 + n * 16 + lr;
        const float g3v = g3[col], b3v = b3[col];
#pragma unroll
        for (int m = 0; m < 4; ++m)
#pragma unroll
            for (int j = 0; j < 4; ++j) {
                const size_t row = rowBase + wr * 64 + m * 16 + rb + j;
                float x = query[row * 512 + col] +
                          (acc[m][n][j] - m3[m][j]) * r3[m][j] * g3v + b3v;
                acc[m][n][j] = x;
                s1[m][j] += x;
                s2[m][j] += x * x;
            }
    }
#pragma unroll
    for (int m = 0; m < 4; ++m)
#pragma unroll
        for (int j = 0; j < 4; ++j)
#pragma unroll
            for (int o = 1; o < 16; o <<= 1) {
                s1[m][j] += __shfl_xor(s1[m][j], o);
                s2[m][j] += __shfl_xor(s2[m][j], o);
            }
    if (lr == 0) {
#pragma unroll
        for (int m = 0; m < 4; ++m)
#pragma unroll
            for (int j = 0; j < 4; ++j)
                rsum2[wr * 64 + m * 16 + rb + j][wc] = make_float2(s1[m][j], s2[m][j]);
    }
    __syncthreads();
#pragma unroll
    for (int m = 0; m < 4; ++m)
#pragma unroll
        for (int j = 0; j < 4; ++j) {
            const int rl = wr * 64 + m * 16 + rb + j;
            float ts = 0.f, ts2 = 0.f;
#pragma unroll
            for (int w = 0; w < 4; ++w) { ts += rsum2[rl][w].x; ts2 += rsum2[rl][w].y; }
            const float mu = ts * (1.f / 512.f);
            m3[m][j] = mu;
            r3[m][j] = rsqrtf(ts2 * (1.f / 512.f) - mu * mu + LN_EPS);
        }
#pragma unroll
    for (int n = 0; n < 8; ++n) {
        const int col = wc * 128 + n * 16 + lr;
        const float gv = g1[col], bv = b1[col];
#pragma unroll
        for (int m = 0; m < 4; ++m)
#pragma unroll
            for (int j = 0; j < 4; ++j) {
                const size_t row = rowBase + wr * 64 + m * 16 + rb + j;
                outp[row * 512 + col] = (acc[m][n][j] - m3[m][j]) * r3[m][j] * gv + bv;
            }
    }
}

extern "C" void kernel_launch(void* const* d_in, const int* in_sizes, int n_in,
                              void* d_out, int out_size, void* d_ws, size_t ws_size,
                              hipStream_t stream) {
    const float* query = (const float*)d_in[0];
    const float* value = (const float*)d_in[1];
    const float* mem_key = (const float*)d_in[2];
    const float* mem_value = (const float*)d_in[3];
    const float* q_w = (const float*)d_in[4];
    const float* q_b = (const float*)d_in[5];
    const float* v_w = (const float*)d_in[6];
    const float* v_b = (const float*)d_in[7];
    const float* out_w = (const float*)d_in[8];
    const float* out_b = (const float*)d_in[9];
    const float* ln1_g = (const float*)d_in[10];
    const float* ln1_b = (const float*)d_in[11];
    const float* ln3_g = (const float*)d_in[12];
    const float* ln3_b = (const float*)d_in[13];
    float* out = (float*)d_out;

    char* ws = (char*)d_ws;
    size_t off = 0;
    auto alloc = [&](size_t bytes) {
        void* p = ws + off;
        off += (bytes + 255) & ~(size_t)255;
        return p;
    };
    bf16_t* bufB = (bf16_t*)alloc(16777216ull * 2);    // qp_bf16, then v_proj_bf16
    bf16_t* addr = (bf16_t*)alloc(32768ull * 896 * 2); // addr, later addr2
    bf16_t* qwb = (bf16_t*)alloc(262144ull * 2);
    bf16_t* vwb = (bf16_t*)alloc(262144ull * 2);
    bf16_t* owb = (bf16_t*)alloc(2097152ull * 2);
    bf16_t* wct = (bf16_t*)alloc(896ull * 512 * 2);    // WcT[512][896]
    bf16_t* keyn = (bf16_t*)alloc(896ull * 64 * 2);
    bf16_t* mvb = (bf16_t*)alloc(128ull * 512 * 2);    // padded to 128 rows
    bf16_t* mvT = (bf16_t*)alloc(512ull * 128 * 2);
    float* invmv = (float*)alloc(112 * 4);
    bf16_t* addr2 = addr;

    float* f_predict = out;
    float* f_recon = out + 16777216;
    float* loss_slots = out + 33554432;  // [recon_loss, contrastive_loss]

    // prep
    cast_k<<<256, 256, 0, stream>>>(q_w, qwb, 65536);
    cast_k<<<256, 256, 0, stream>>>(v_w, vwb, 65536);
    cast_k<<<2048, 256, 0, stream>>>(out_w, owb, 524288);
    keyn_k<<<224, 256, 0, stream>>>(mem_key, keyn);
    mv_prep_k<<<128, 256, 0, stream>>>(mem_value, mvb, invmv, loss_slots);
    mvT_k<<<256, 256, 0, stream>>>(mem_value, mvT);
    contrastive_k<<<112, 256, 0, stream>>>(mem_value, invmv, loss_slots + 1);
    // WcT[d][h*112+s] = sum_j out_w[d][h*512+j] * mem_value[s][j]
    gemm_bt<<<dim3(8, 2, 8), 256, 0, stream>>>(owb, 4096, 512, mvb, 512, 0,
                                               wct, 896, 112, 512, 112, 512);
    // predict branch
    gemm128_f32a<<<dim3(256, 4), 256, 0, stream>>>(query, 512, qwb, 512, q_b,
                                                   bufB, 512, 512);
    addr_predict<<<dim3(512, 8), 256, 0, stream>>>(bufB, keyn, addr);
    gemm_ln_predict<<<256, 512, 0, stream>>>(addr, wct, out_b, query,
                                             ln1_g, ln1_b, f_predict);
    // recon branch
    gemm128_f32a<<<dim3(256, 4), 256, 0, stream>>>(value, 512, vwb, 512, v_b,
                                                   bufB, 512, 512);
    gemm_sim_softmax<<<256, 256, 0, stream>>>(bufB, mvb, invmv, addr2);
    gemm_ln_recon<<<256, 512, 0, stream>>>(addr2, mvT, query, value,
                                           ln3_g, ln3_b, ln1_g, ln1_b,
                                           f_recon, loss_slots);
}